// Round 1
// baseline (737.837 us; speedup 1.0000x reference)
//
#include <hip/hip_runtime.h>
#include <math.h>

// ---------------------------------------------------------------------------
// FASA fp32 pipeline for MI355X. B=4, C=128, H=W=128, HEADS=4, dh=32, pool->32x32
// ---------------------------------------------------------------------------

#define NB   4
#define NC   128
#define NH   128
#define NW   128
#define NHW  16384      // 128*128
#define NKV  1024       // 32*32

// ---------------------------------------------------------------------------
// Pointwise 1x1 conv as GEMM: Y[b][m0+m][pos] = bias[m] + sum_c W[m][c]*X[b][c][pos]
// K = 128 fixed. BM=128, BN=64, BK=32; 256 threads; 8x4 register tile.
// ---------------------------------------------------------------------------
__global__ __launch_bounds__(256) void pw_gemm(
    const float* __restrict__ Wmat,   // [Mtot][128] row-major
    const float* __restrict__ bias,   // [Mtot]
    const float* __restrict__ X,      // [B][128][npos]
    float* __restrict__ Y,            // [B][Mtot][npos]
    int npos)
{
  __shared__ float As[32][128];   // [k][m]
  __shared__ float Bs[32][68];    // [k][n], padded to break row-alias banks

  const int t  = threadIdx.x;
  const int b  = blockIdx.z;
  const int m0 = blockIdx.y * 128;
  const int n0 = blockIdx.x * 64;
  const int Mtot = gridDim.y * 128;

  const float* Xb = X + (size_t)b * 128 * npos;
  float* Yb = Y + ((size_t)b * Mtot + m0) * npos;

  const int og = t >> 4;          // 0..15 -> m = og*8 .. og*8+7
  const int pg = t & 15;          // 0..15 -> n = pg*4 .. pg*4+3

  float acc[8][4];
  #pragma unroll
  for (int i = 0; i < 8; i++)
    #pragma unroll
    for (int j = 0; j < 4; j++) acc[i][j] = 0.f;

  const int am  = t & 127;        // A tile row
  const int aq0 = t >> 7;         // 0/1
  const int bn  = (t & 15) * 4;   // B tile col (float4)
  const int bc0 = t >> 4;         // B tile rows bc0, bc0+16

  for (int k0 = 0; k0 < 128; k0 += 32) {
    // stage A transposed: As[k][m] = W[m0+m][k0+k]
    #pragma unroll
    for (int i = 0; i < 4; i++) {
      int q = aq0 + 2 * i;        // 0..7
      float4 a = *(const float4*)&Wmat[(size_t)(m0 + am) * 128 + k0 + 4 * q];
      As[4*q+0][am] = a.x; As[4*q+1][am] = a.y;
      As[4*q+2][am] = a.z; As[4*q+3][am] = a.w;
    }
    // stage B: Bs[c][n] = X[b][k0+c][n0+n]
    #pragma unroll
    for (int i = 0; i < 2; i++) {
      int c = bc0 + 16 * i;       // 0..31
      float4 v = *(const float4*)&Xb[(size_t)(k0 + c) * npos + n0 + bn];
      *(float4*)&Bs[c][bn] = v;
    }
    __syncthreads();
    #pragma unroll
    for (int k = 0; k < 32; k++) {
      float4 a0 = *(const float4*)&As[k][og * 8];
      float4 a1 = *(const float4*)&As[k][og * 8 + 4];
      float4 bv = *(const float4*)&Bs[k][pg * 4];
      float av[8] = {a0.x, a0.y, a0.z, a0.w, a1.x, a1.y, a1.z, a1.w};
      float bw[4] = {bv.x, bv.y, bv.z, bv.w};
      #pragma unroll
      for (int i = 0; i < 8; i++)
        #pragma unroll
        for (int j = 0; j < 4; j++)
          acc[i][j] += av[i] * bw[j];
    }
    __syncthreads();
  }

  #pragma unroll
  for (int i = 0; i < 8; i++) {
    int m = og * 8 + i;
    float bs = bias[m0 + m];
    float4 o;
    o.x = acc[i][0] + bs; o.y = acc[i][1] + bs;
    o.z = acc[i][2] + bs; o.w = acc[i][3] + bs;
    *(float4*)&Yb[(size_t)m * npos + n0 + pg * 4] = o;
  }
}

// ---------------------------------------------------------------------------
// Depthwise 5x5 conv, pad 2, stride S, fused inference BN.
// out = ((conv + bias) - mean) * g/sqrt(var+eps) + beta
// ---------------------------------------------------------------------------
template<int S>
__global__ __launch_bounds__(256) void dw5x5_bn(
    const float* __restrict__ in, int Hin, int Win,
    const float* __restrict__ wt, const float* __restrict__ bias,
    const float* __restrict__ g, const float* __restrict__ bt,
    const float* __restrict__ mean, const float* __restrict__ var,
    float* __restrict__ out, int Hout, int Wout)
{
  const int c = blockIdx.y;
  const int b = blockIdx.z;
  const int p = blockIdx.x * 256 + threadIdx.x;
  const int y = p / Wout, x = p % Wout;
  const float* plane = in + ((size_t)b * NC + c) * Hin * Win;

  float a = 0.f;
  #pragma unroll
  for (int i = 0; i < 5; i++) {
    int iy = y * S - 2 + i;
    if (iy < 0 || iy >= Hin) continue;
    #pragma unroll
    for (int j = 0; j < 5; j++) {
      int ix = x * S - 2 + j;
      if (ix < 0 || ix >= Win) continue;
      a += wt[c * 25 + i * 5 + j] * plane[(size_t)iy * Win + ix];
    }
  }
  a += bias[c];
  float sc = g[c] * rsqrtf(var[c] + 1e-5f);
  a = (a - mean[c]) * sc + bt[c];
  out[((size_t)b * NC + c) * Hout * Wout + p] = a;
}

// ---------------------------------------------------------------------------
// kv [4][256][1024] -> kvT [4][2][4][1024][32]   (b, s, h, kpos, d)
// ---------------------------------------------------------------------------
__global__ __launch_bounds__(256) void kv_transpose(
    const float* __restrict__ kv, float* __restrict__ kvT)
{
  int idx = blockIdx.x * 256 + threadIdx.x;  // 2^20 total
  int d    = idx & 31;
  int kpos = (idx >> 5) & 1023;
  int h    = (idx >> 15) & 3;
  int s    = (idx >> 17) & 1;
  int b    = idx >> 18;
  kvT[idx] = kv[((size_t)b * 256 + s * 128 + h * 32 + d) * NKV + kpos];
}

// ---------------------------------------------------------------------------
// Attention: thread-per-query flash loop, no max-subtraction (scores are tiny).
// gf[b][h*32+d][q] = sum_k softmax_k(scale*q.k) * v[k][d]
// ---------------------------------------------------------------------------
__global__ __launch_bounds__(256) void attn_kernel(
    const float* __restrict__ q_local,   // [4][128][16384]
    const float* __restrict__ kvT,       // [4][2][4][1024][32]
    float* __restrict__ gf)              // [4][128][16384]
{
  const int b = blockIdx.z;
  const int h = blockIdx.y;
  const int qpos = blockIdx.x * 256 + threadIdx.x;

  const float scale = 0.17677669529663689f;   // 1/sqrt(32)
  const float* qbase = q_local + ((size_t)b * NC + h * 32) * NHW + qpos;

  float qv[32];
  #pragma unroll
  for (int d = 0; d < 32; d++) qv[d] = qbase[(size_t)d * NHW] * scale;

  const float* kb = kvT + (((size_t)b * 2 + 0) * 4 + h) * NKV * 32;
  const float* vb = kvT + (((size_t)b * 2 + 1) * 4 + h) * NKV * 32;

  float acc[32];
  #pragma unroll
  for (int d = 0; d < 32; d++) acc[d] = 0.f;
  float l = 0.f;

  #pragma unroll 2
  for (int kp = 0; kp < NKV; kp++) {
    const float4* kr = (const float4*)(kb + kp * 32);
    float s = 0.f;
    #pragma unroll
    for (int q = 0; q < 8; q++) {
      float4 kk = kr[q];
      s += qv[4*q+0] * kk.x + qv[4*q+1] * kk.y
         + qv[4*q+2] * kk.z + qv[4*q+3] * kk.w;
    }
    float pexp = __expf(s);
    l += pexp;
    const float4* vr = (const float4*)(vb + kp * 32);
    #pragma unroll
    for (int q = 0; q < 8; q++) {
      float4 vv = vr[q];
      acc[4*q+0] += pexp * vv.x; acc[4*q+1] += pexp * vv.y;
      acc[4*q+2] += pexp * vv.z; acc[4*q+3] += pexp * vv.w;
    }
  }

  float inv = 1.f / l;
  float* gbase = gf + ((size_t)b * NC + h * 32) * NHW + qpos;
  #pragma unroll
  for (int d = 0; d < 32; d++) gbase[(size_t)d * NHW] = acc[d] * inv;
}

// ---------------------------------------------------------------------------
// lf = dw5x5(q_local) + local_b (stride 1); t = lf*sig(lf)*sig(gf)*gf
// ---------------------------------------------------------------------------
__global__ __launch_bounds__(256) void lf_fuse(
    const float* __restrict__ qloc, const float* __restrict__ gf,
    const float* __restrict__ wt, const float* __restrict__ bias,
    float* __restrict__ tout)
{
  const int c = blockIdx.y;
  const int b = blockIdx.z;
  const int p = blockIdx.x * 256 + threadIdx.x;
  const int y = p >> 7, x = p & 127;
  const float* plane = qloc + ((size_t)b * NC + c) * NHW;

  float a = 0.f;
  #pragma unroll
  for (int i = 0; i < 5; i++) {
    int iy = y - 2 + i;
    if (iy < 0 || iy >= NH) continue;
    #pragma unroll
    for (int j = 0; j < 5; j++) {
      int ix = x - 2 + j;
      if (ix < 0 || ix >= NW) continue;
      a += wt[c * 25 + i * 5 + j] * plane[iy * NW + ix];
    }
  }
  a += bias[c];
  float gv = gf[((size_t)b * NC + c) * NHW + p];
  float sl = a / (1.f + __expf(-a));      // lf * sigmoid(lf)
  float sg = 1.f / (1.f + __expf(-gv));   // sigmoid(gf)
  tout[((size_t)b * NC + c) * NHW + p] = sl * sg * gv;
}

// ---------------------------------------------------------------------------
extern "C" void kernel_launch(void* const* d_in, const int* in_sizes, int n_in,
                              void* d_out, int out_size, void* d_ws, size_t ws_size,
                              hipStream_t stream) {
  const float* x       = (const float*)d_in[0];
  const float* q_w     = (const float*)d_in[1];
  const float* q_b     = (const float*)d_in[2];
  const float* kv_w    = (const float*)d_in[3];
  const float* kv_b    = (const float*)d_in[4];
  const float* local_w = (const float*)d_in[5];
  const float* local_b = (const float*)d_in[6];
  const float* mixer_w = (const float*)d_in[7];
  const float* mixer_b = (const float*)d_in[8];
  const float* p0_w    = (const float*)d_in[9];
  const float* p0_b    = (const float*)d_in[10];
  const float* bn0_g   = (const float*)d_in[11];
  const float* bn0_b   = (const float*)d_in[12];
  const float* bn0_m   = (const float*)d_in[13];
  const float* bn0_v   = (const float*)d_in[14];
  const float* lin0_w  = (const float*)d_in[15];
  const float* lin0_b  = (const float*)d_in[16];
  const float* p1_w    = (const float*)d_in[17];
  const float* p1_b    = (const float*)d_in[18];
  const float* bn1_g   = (const float*)d_in[19];
  const float* bn1_b   = (const float*)d_in[20];
  const float* bn1_m   = (const float*)d_in[21];
  const float* bn1_v   = (const float*)d_in[22];

  float* ws = (float*)d_ws;
  float* q_local = ws;                     // 8,388,608 floats
  float* gf      = ws + 8388608;           // 8,388,608
  float* tbuf    = ws + 16777216;          // 8,388,608
  float* p0      = ws + 25165824;          // 2,097,152  (4x128x64x64)
  float* lin0b   = ws + 27262976;          // 2,097,152
  float* p1      = ws + 29360128;          // 524,288    (4x128x32x32)
  float* kvb     = ws + 29884416;          // 1,048,576  (4x256x32x32)
  float* kvT     = ws + 30932992;          // 1,048,576
  // total 31,981,568 floats = ~122 MB

  // 1) q_local = pw(x, q_w) + q_b
  pw_gemm<<<dim3(NHW / 64, 1, NB), 256, 0, stream>>>(q_w, q_b, x, q_local, NHW);
  // 2) p0 = bn0(dw5x5_s2(x) + p0_b)          -> 64x64
  dw5x5_bn<2><<<dim3(4096 / 256, NC, NB), 256, 0, stream>>>(
      x, NH, NW, p0_w, p0_b, bn0_g, bn0_b, bn0_m, bn0_v, p0, 64, 64);
  // 3) lin0 = pw(p0, lin0_w) + lin0_b
  pw_gemm<<<dim3(4096 / 64, 1, NB), 256, 0, stream>>>(lin0_w, lin0_b, p0, lin0b, 4096);
  // 4) p1 = bn1(dw5x5_s2(lin0) + p1_b)       -> 32x32
  dw5x5_bn<2><<<dim3(1024 / 256, NC, NB), 256, 0, stream>>>(
      lin0b, 64, 64, p1_w, p1_b, bn1_g, bn1_b, bn1_m, bn1_v, p1, 32, 32);
  // 5) kv = pw(p1, kv_w) + kv_b   (256 out channels)
  pw_gemm<<<dim3(NKV / 64, 2, NB), 256, 0, stream>>>(kv_w, kv_b, p1, kvb, NKV);
  // 6) transpose kv -> [b][s][h][kpos][d]
  kv_transpose<<<dim3(1048576 / 256), 256, 0, stream>>>(kvb, kvT);
  // 7) attention -> gf
  attn_kernel<<<dim3(NHW / 256, 4, NB), 256, 0, stream>>>(q_local, kvT, gf);
  // 8) lf dwconv + elementwise fuse -> tbuf
  lf_fuse<<<dim3(NHW / 256, NC, NB), 256, 0, stream>>>(q_local, gf, local_w, local_b, tbuf);
  // 9) out = pw(tbuf, mixer_w) + mixer_b
  pw_gemm<<<dim3(NHW / 64, 1, NB), 256, 0, stream>>>(mixer_w, mixer_b, tbuf, (float*)d_out, NHW);
}

// Round 3
// 424.600 us; speedup vs baseline: 1.7377x; 1.7377x over previous
//
#include <hip/hip_runtime.h>
#include <hip/hip_bf16.h>
#include <math.h>

// ---------------------------------------------------------------------------
// FASA pipeline for MI355X. B=4, C=128, H=W=128, HEADS=4, dh=32, pool->32x32
// Round 3: bf16 MFMA flash attention (compile fix: manual bf16x2 packing).
// ---------------------------------------------------------------------------

#define NB   4
#define NC   128
#define NH   128
#define NW   128
#define NHW  16384      // 128*128
#define NKV  1024       // 32*32

typedef float  f32x4  __attribute__((ext_vector_type(4)));
typedef short  bf16x8 __attribute__((ext_vector_type(8)));

__device__ __forceinline__ unsigned short f2bf(float f) {
  unsigned u = __float_as_uint(f);
  u += 0x7FFF + ((u >> 16) & 1);      // round to nearest even
  return (unsigned short)(u >> 16);
}

__device__ __forceinline__ unsigned pk2(float a, float b) {
  return (unsigned)f2bf(a) | ((unsigned)f2bf(b) << 16);
}

// ---------------------------------------------------------------------------
// Pointwise 1x1 conv as GEMM: Y[b][m0+m][pos] = bias[m] + sum_c W[m][c]*X[b][c][pos]
// ---------------------------------------------------------------------------
__global__ __launch_bounds__(256) void pw_gemm(
    const float* __restrict__ Wmat,   // [Mtot][128] row-major
    const float* __restrict__ bias,   // [Mtot]
    const float* __restrict__ X,      // [B][128][npos]
    float* __restrict__ Y,            // [B][Mtot][npos]
    int npos)
{
  __shared__ float As[32][128];   // [k][m]
  __shared__ float Bs[32][68];    // [k][n]

  const int t  = threadIdx.x;
  const int b  = blockIdx.z;
  const int m0 = blockIdx.y * 128;
  const int n0 = blockIdx.x * 64;
  const int Mtot = gridDim.y * 128;

  const float* Xb = X + (size_t)b * 128 * npos;
  float* Yb = Y + ((size_t)b * Mtot + m0) * npos;

  const int og = t >> 4;
  const int pg = t & 15;

  float acc[8][4];
  #pragma unroll
  for (int i = 0; i < 8; i++)
    #pragma unroll
    for (int j = 0; j < 4; j++) acc[i][j] = 0.f;

  const int am  = t & 127;
  const int aq0 = t >> 7;
  const int bn  = (t & 15) * 4;
  const int bc0 = t >> 4;

  for (int k0 = 0; k0 < 128; k0 += 32) {
    #pragma unroll
    for (int i = 0; i < 4; i++) {
      int q = aq0 + 2 * i;
      float4 a = *(const float4*)&Wmat[(size_t)(m0 + am) * 128 + k0 + 4 * q];
      As[4*q+0][am] = a.x; As[4*q+1][am] = a.y;
      As[4*q+2][am] = a.z; As[4*q+3][am] = a.w;
    }
    #pragma unroll
    for (int i = 0; i < 2; i++) {
      int c = bc0 + 16 * i;
      float4 v = *(const float4*)&Xb[(size_t)(k0 + c) * npos + n0 + bn];
      *(float4*)&Bs[c][bn] = v;
    }
    __syncthreads();
    #pragma unroll
    for (int k = 0; k < 32; k++) {
      float4 a0 = *(const float4*)&As[k][og * 8];
      float4 a1 = *(const float4*)&As[k][og * 8 + 4];
      float4 bv = *(const float4*)&Bs[k][pg * 4];
      float av[8] = {a0.x, a0.y, a0.z, a0.w, a1.x, a1.y, a1.z, a1.w};
      float bw[4] = {bv.x, bv.y, bv.z, bv.w};
      #pragma unroll
      for (int i = 0; i < 8; i++)
        #pragma unroll
        for (int j = 0; j < 4; j++)
          acc[i][j] += av[i] * bw[j];
    }
    __syncthreads();
  }

  #pragma unroll
  for (int i = 0; i < 8; i++) {
    int m = og * 8 + i;
    float bs = bias[m0 + m];
    float4 o;
    o.x = acc[i][0] + bs; o.y = acc[i][1] + bs;
    o.z = acc[i][2] + bs; o.w = acc[i][3] + bs;
    *(float4*)&Yb[(size_t)m * npos + n0 + pg * 4] = o;
  }
}

// ---------------------------------------------------------------------------
// Depthwise 5x5 conv, pad 2, stride S, fused inference BN.
// ---------------------------------------------------------------------------
template<int S>
__global__ __launch_bounds__(256) void dw5x5_bn(
    const float* __restrict__ in, int Hin, int Win,
    const float* __restrict__ wt, const float* __restrict__ bias,
    const float* __restrict__ g, const float* __restrict__ bt,
    const float* __restrict__ mean, const float* __restrict__ var,
    float* __restrict__ out, int Hout, int Wout)
{
  const int c = blockIdx.y;
  const int b = blockIdx.z;
  const int p = blockIdx.x * 256 + threadIdx.x;
  const int y = p / Wout, x = p % Wout;
  const float* plane = in + ((size_t)b * NC + c) * Hin * Win;

  float a = 0.f;
  #pragma unroll
  for (int i = 0; i < 5; i++) {
    int iy = y * S - 2 + i;
    if (iy < 0 || iy >= Hin) continue;
    #pragma unroll
    for (int j = 0; j < 5; j++) {
      int ix = x * S - 2 + j;
      if (ix < 0 || ix >= Win) continue;
      a += wt[c * 25 + i * 5 + j] * plane[(size_t)iy * Win + ix];
    }
  }
  a += bias[c];
  float sc = g[c] * rsqrtf(var[c] + 1e-5f);
  a = (a - mean[c]) * sc + bt[c];
  out[((size_t)b * NC + c) * Hout * Wout + p] = a;
}

// ---------------------------------------------------------------------------
// kv prep: kvb fp32 [4][256][1024] -> kT bf16 [16][1024][32], vT bf16 [16][32][1024]
// ---------------------------------------------------------------------------
__global__ __launch_bounds__(256) void kv_prep(
    const float* __restrict__ kvb,
    short* __restrict__ kT, short* __restrict__ vT)
{
  const int t = threadIdx.x;
  const int h = blockIdx.y, b = blockIdx.z;
  const int kpos = blockIdx.x * 256 + t;
  const int bh = b * 4 + h;

  bf16x8 kr[4];
  #pragma unroll
  for (int d = 0; d < 32; d++) {
    float kvv = kvb[((size_t)b * 256 + h * 32 + d) * NKV + kpos];
    float vvv = kvb[((size_t)b * 256 + 128 + h * 32 + d) * NKV + kpos];
    kr[d >> 3][d & 7] = (short)f2bf(kvv);
    vT[(size_t)bh * 32768 + d * NKV + kpos] = (short)f2bf(vvv);
  }
  short* dst = kT + (size_t)bh * 32768 + (size_t)kpos * 32;
  #pragma unroll
  for (int i = 0; i < 4; i++)
    *(bf16x8*)(dst + i * 8) = kr[i];
}

// ---------------------------------------------------------------------------
// MFMA flash attention. Per wave: 16 q rows, loop 32-key tiles.
// Swapped QK^T: S^T = mfma(K, Q^T)  -> D: col=q, row=key
// PV: O^T = mfma(V^T, P^T)          -> D: col=q, row=d   == gf layout
// ---------------------------------------------------------------------------
__global__ __launch_bounds__(256) void attn_mfma(
    const float* __restrict__ q_local,   // [4][128][16384] fp32
    const short* __restrict__ kT,        // [16][1024][32] bf16
    const short* __restrict__ vT,        // [16][32][1024] bf16
    float* __restrict__ gf)              // [4][128][16384] fp32
{
  __shared__ short Pt[4 * 16 * 40] __attribute__((aligned(16)));   // per-wave [q=c][40]

  const int t    = threadIdx.x;
  const int w    = t >> 6;
  const int lane = t & 63;
  const int c    = lane & 15;
  const int g    = lane >> 4;
  const int b    = blockIdx.z, h = blockIdx.y;
  const int q0   = blockIdx.x * 64 + w * 16;
  const int bh   = b * 4 + h;

  // Q fragment: Q^T B-operand. lane: q = q0+c, d = 8g+e.  scale*log2e folded in.
  const float QSCALE = 0.17677669529663689f * 1.4426950408889634f;
  bf16x8 qf;
  {
    const float* qbase = q_local + ((size_t)(b * NC + h * 32 + 8 * g)) * NHW + q0 + c;
    #pragma unroll
    for (int e = 0; e < 8; e++)
      qf[e] = (short)f2bf(qbase[(size_t)e * NHW] * QSCALE);
  }

  const short* kbh = kT + (size_t)bh * 32768;
  const short* vbh = vT + (size_t)bh * 32768;
  short* ptw = &Pt[w * 640];

  f32x4 o0 = {0.f, 0.f, 0.f, 0.f};
  f32x4 o1 = {0.f, 0.f, 0.f, 0.f};
  const f32x4 zf = {0.f, 0.f, 0.f, 0.f};
  float lsum = 0.f;

  for (int kt = 0; kt < 32; kt++) {
    const int k0 = kt * 32;
    // K fragments: A-operand rows = keys. lane: key = k0 + c (+16), d = 8g..8g+7
    bf16x8 ak0 = *(const bf16x8*)(kbh + (size_t)(k0 + c) * 32 + 8 * g);
    bf16x8 ak1 = *(const bf16x8*)(kbh + (size_t)(k0 + 16 + c) * 32 + 8 * g);
    f32x4 s0 = __builtin_amdgcn_mfma_f32_16x16x32_bf16(ak0, qf, zf, 0, 0, 0);
    f32x4 s1 = __builtin_amdgcn_mfma_f32_16x16x32_bf16(ak1, qf, zf, 0, 0, 0);

    // exp2 softmax numerators; lane holds q=c, keys k0 + 4g+r (s0) / k0+16+4g+r (s1)
    float e0[4], e1[4];
    #pragma unroll
    for (int r = 0; r < 4; r++) {
      e0[r] = __builtin_amdgcn_exp2f(s0[r]);
      e1[r] = __builtin_amdgcn_exp2f(s1[r]);
    }
    lsum += (e0[0] + e0[1]) + (e0[2] + e0[3]) + (e1[0] + e1[1]) + (e1[2] + e1[3]);

    // P -> LDS (bf16), layout [q=c][key_local]
    uint2 u0; u0.x = pk2(e0[0], e0[1]); u0.y = pk2(e0[2], e0[3]);
    uint2 u1; u1.x = pk2(e1[0], e1[1]); u1.y = pk2(e1[2], e1[3]);
    *(uint2*)&ptw[c * 40 + 4 * g]      = u0;   // keys 4g..4g+3
    *(uint2*)&ptw[c * 40 + 16 + 4 * g] = u1;   // keys 16+4g..16+4g+3

    // P^T B-operand: lane: q = c, keys 8g..8g+7
    bf16x8 bp = *(const bf16x8*)&ptw[c * 40 + 8 * g];

    // V^T A-operand: lane: d = c (+16), keys k0 + 8g..8g+7
    bf16x8 av0 = *(const bf16x8*)(vbh + (size_t)c * NKV + k0 + 8 * g);
    bf16x8 av1 = *(const bf16x8*)(vbh + (size_t)(16 + c) * NKV + k0 + 8 * g);
    o0 = __builtin_amdgcn_mfma_f32_16x16x32_bf16(av0, bp, o0, 0, 0, 0);
    o1 = __builtin_amdgcn_mfma_f32_16x16x32_bf16(av1, bp, o1, 0, 0, 0);
  }

  // total row sum for q=c: reduce across the 4 lane-groups
  lsum += __shfl_xor(lsum, 16);
  lsum += __shfl_xor(lsum, 32);
  float inv = 1.f / lsum;

  // store O^T: D row = d = 4g+r (o0) / 16+4g+r (o1), col = q = c  -> gf[d][qpos]
  float* gfb = gf + ((size_t)(b * NC + h * 32)) * NHW + q0 + c;
  #pragma unroll
  for (int r = 0; r < 4; r++) {
    gfb[(size_t)(4 * g + r) * NHW]      = o0[r] * inv;
    gfb[(size_t)(16 + 4 * g + r) * NHW] = o1[r] * inv;
  }
}

// ---------------------------------------------------------------------------
// lf = dw5x5(q_local) + local_b (stride 1); t = lf*sig(lf)*sig(gf)*gf
// ---------------------------------------------------------------------------
__global__ __launch_bounds__(256) void lf_fuse(
    const float* __restrict__ qloc, const float* __restrict__ gf,
    const float* __restrict__ wt, const float* __restrict__ bias,
    float* __restrict__ tout)
{
  const int c = blockIdx.y;
  const int b = blockIdx.z;
  const int p = blockIdx.x * 256 + threadIdx.x;
  const int y = p >> 7, x = p & 127;
  const float* plane = qloc + ((size_t)b * NC + c) * NHW;

  float a = 0.f;
  #pragma unroll
  for (int i = 0; i < 5; i++) {
    int iy = y - 2 + i;
    if (iy < 0 || iy >= NH) continue;
    #pragma unroll
    for (int j = 0; j < 5; j++) {
      int ix = x - 2 + j;
      if (ix < 0 || ix >= NW) continue;
      a += wt[c * 25 + i * 5 + j] * plane[iy * NW + ix];
    }
  }
  a += bias[c];
  float gv = gf[((size_t)b * NC + c) * NHW + p];
  float sl = a / (1.f + __expf(-a));
  float sg = 1.f / (1.f + __expf(-gv));
  tout[((size_t)b * NC + c) * NHW + p] = sl * sg * gv;
}

// ---------------------------------------------------------------------------
extern "C" void kernel_launch(void* const* d_in, const int* in_sizes, int n_in,
                              void* d_out, int out_size, void* d_ws, size_t ws_size,
                              hipStream_t stream) {
  const float* x       = (const float*)d_in[0];
  const float* q_w     = (const float*)d_in[1];
  const float* q_b     = (const float*)d_in[2];
  const float* kv_w    = (const float*)d_in[3];
  const float* kv_b    = (const float*)d_in[4];
  const float* local_w = (const float*)d_in[5];
  const float* local_b = (const float*)d_in[6];
  const float* mixer_w = (const float*)d_in[7];
  const float* mixer_b = (const float*)d_in[8];
  const float* p0_w    = (const float*)d_in[9];
  const float* p0_b    = (const float*)d_in[10];
  const float* bn0_g   = (const float*)d_in[11];
  const float* bn0_b   = (const float*)d_in[12];
  const float* bn0_m   = (const float*)d_in[13];
  const float* bn0_v   = (const float*)d_in[14];
  const float* lin0_w  = (const float*)d_in[15];
  const float* lin0_b  = (const float*)d_in[16];
  const float* p1_w    = (const float*)d_in[17];
  const float* p1_b    = (const float*)d_in[18];
  const float* bn1_g   = (const float*)d_in[19];
  const float* bn1_b   = (const float*)d_in[20];
  const float* bn1_m   = (const float*)d_in[21];
  const float* bn1_v   = (const float*)d_in[22];

  float* ws = (float*)d_ws;
  float* q_local = ws;                     // 8,388,608 floats
  float* gf      = ws + 8388608;           // 8,388,608
  float* tbuf    = ws + 16777216;          // 8,388,608
  float* p0      = ws + 25165824;          // 2,097,152
  float* lin0b   = ws + 27262976;          // 2,097,152
  float* p1      = ws + 29360128;          // 524,288
  float* kvb     = ws + 29884416;          // 1,048,576  (4x256x1024)
  short* kT      = (short*)(ws + 30932992);    // 524,288 shorts = 1 MB
  short* vT      = kT + 524288;                // 524,288 shorts

  // 1) q_local = pw(x, q_w) + q_b
  pw_gemm<<<dim3(NHW / 64, 1, NB), 256, 0, stream>>>(q_w, q_b, x, q_local, NHW);
  // 2) p0 = bn0(dw5x5_s2(x) + p0_b)          -> 64x64
  dw5x5_bn<2><<<dim3(4096 / 256, NC, NB), 256, 0, stream>>>(
      x, NH, NW, p0_w, p0_b, bn0_g, bn0_b, bn0_m, bn0_v, p0, 64, 64);
  // 3) lin0 = pw(p0, lin0_w) + lin0_b
  pw_gemm<<<dim3(4096 / 64, 1, NB), 256, 0, stream>>>(lin0_w, lin0_b, p0, lin0b, 4096);
  // 4) p1 = bn1(dw5x5_s2(lin0) + p1_b)       -> 32x32
  dw5x5_bn<2><<<dim3(1024 / 256, NC, NB), 256, 0, stream>>>(
      lin0b, 64, 64, p1_w, p1_b, bn1_g, bn1_b, bn1_m, bn1_v, p1, 32, 32);
  // 5) kv = pw(p1, kv_w) + kv_b   (256 out channels)
  pw_gemm<<<dim3(NKV / 64, 2, NB), 256, 0, stream>>>(kv_w, kv_b, p1, kvb, NKV);
  // 6) kv -> bf16 kT [bh][kpos][32], vT [bh][d][kpos]
  kv_prep<<<dim3(4, 4, NB), 256, 0, stream>>>(kvb, kT, vT);
  // 7) MFMA attention -> gf
  attn_mfma<<<dim3(256, 4, NB), 256, 0, stream>>>(q_local, kT, vT, gf);
  // 8) lf dwconv + elementwise fuse -> tbuf
  lf_fuse<<<dim3(NHW / 256, NC, NB), 256, 0, stream>>>(q_local, gf, local_w, local_b, tbuf);
  // 9) out = pw(tbuf, mixer_w) + mixer_b
  pw_gemm<<<dim3(NHW / 64, 1, NB), 256, 0, stream>>>(mixer_w, mixer_b, tbuf, (float*)d_out, NHW);
}

// Round 4
// 343.501 us; speedup vs baseline: 2.1480x; 1.2361x over previous
//
#include <hip/hip_runtime.h>
#include <hip/hip_bf16.h>
#include <math.h>

// ---------------------------------------------------------------------------
// FASA pipeline for MI355X. B=4, C=128, H=W=128, HEADS=4, dh=32, pool->32x32
// Round 4: 32x32 MFMA attention, in-register softmax (cvt_pk + shfl_xor 32).
// ---------------------------------------------------------------------------

#define NB   4
#define NC   128
#define NH   128
#define NW   128
#define NHW  16384      // 128*128
#define NKV  1024       // 32*32

typedef float    f32x4  __attribute__((ext_vector_type(4)));
typedef float    f32x16 __attribute__((ext_vector_type(16)));
typedef short    bf16x8 __attribute__((ext_vector_type(8)));
typedef unsigned u32x4v __attribute__((ext_vector_type(4)));

__device__ __forceinline__ unsigned short f2bf(float f) {
  unsigned u = __float_as_uint(f);
  u += 0x7FFF + ((u >> 16) & 1);      // round to nearest even
  return (unsigned short)(u >> 16);
}

// pack two f32 -> bf16x2 in one instr (no builtin on gfx950; T12 recipe)
__device__ __forceinline__ unsigned cvtpk(float lo, float hi) {
  unsigned r;
  asm("v_cvt_pk_bf16_f32 %0, %1, %2" : "=v"(r) : "v"(lo), "v"(hi));
  return r;
}

// ---------------------------------------------------------------------------
// Pointwise 1x1 conv as GEMM: Y[b][m0+m][pos] = bias[m] + sum_c W[m][c]*X[b][c][pos]
// ---------------------------------------------------------------------------
__global__ __launch_bounds__(256) void pw_gemm(
    const float* __restrict__ Wmat,   // [Mtot][128] row-major
    const float* __restrict__ bias,   // [Mtot]
    const float* __restrict__ X,      // [B][128][npos]
    float* __restrict__ Y,            // [B][Mtot][npos]
    int npos)
{
  __shared__ float As[32][128];   // [k][m]
  __shared__ float Bs[32][68];    // [k][n]

  const int t  = threadIdx.x;
  const int b  = blockIdx.z;
  const int m0 = blockIdx.y * 128;
  const int n0 = blockIdx.x * 64;
  const int Mtot = gridDim.y * 128;

  const float* Xb = X + (size_t)b * 128 * npos;
  float* Yb = Y + ((size_t)b * Mtot + m0) * npos;

  const int og = t >> 4;
  const int pg = t & 15;

  float acc[8][4];
  #pragma unroll
  for (int i = 0; i < 8; i++)
    #pragma unroll
    for (int j = 0; j < 4; j++) acc[i][j] = 0.f;

  const int am  = t & 127;
  const int aq0 = t >> 7;
  const int bn  = (t & 15) * 4;
  const int bc0 = t >> 4;

  for (int k0 = 0; k0 < 128; k0 += 32) {
    #pragma unroll
    for (int i = 0; i < 4; i++) {
      int q = aq0 + 2 * i;
      float4 a = *(const float4*)&Wmat[(size_t)(m0 + am) * 128 + k0 + 4 * q];
      As[4*q+0][am] = a.x; As[4*q+1][am] = a.y;
      As[4*q+2][am] = a.z; As[4*q+3][am] = a.w;
    }
    #pragma unroll
    for (int i = 0; i < 2; i++) {
      int c = bc0 + 16 * i;
      float4 v = *(const float4*)&Xb[(size_t)(k0 + c) * npos + n0 + bn];
      *(float4*)&Bs[c][bn] = v;
    }
    __syncthreads();
    #pragma unroll
    for (int k = 0; k < 32; k++) {
      float4 a0 = *(const float4*)&As[k][og * 8];
      float4 a1 = *(const float4*)&As[k][og * 8 + 4];
      float4 bv = *(const float4*)&Bs[k][pg * 4];
      float av[8] = {a0.x, a0.y, a0.z, a0.w, a1.x, a1.y, a1.z, a1.w};
      float bw[4] = {bv.x, bv.y, bv.z, bv.w};
      #pragma unroll
      for (int i = 0; i < 8; i++)
        #pragma unroll
        for (int j = 0; j < 4; j++)
          acc[i][j] += av[i] * bw[j];
    }
    __syncthreads();
  }

  #pragma unroll
  for (int i = 0; i < 8; i++) {
    int m = og * 8 + i;
    float bs = bias[m0 + m];
    float4 o;
    o.x = acc[i][0] + bs; o.y = acc[i][1] + bs;
    o.z = acc[i][2] + bs; o.w = acc[i][3] + bs;
    *(float4*)&Yb[(size_t)m * npos + n0 + pg * 4] = o;
  }
}

// ---------------------------------------------------------------------------
// Depthwise 5x5 conv, pad 2, stride S, fused inference BN.
// ---------------------------------------------------------------------------
template<int S>
__global__ __launch_bounds__(256) void dw5x5_bn(
    const float* __restrict__ in, int Hin, int Win,
    const float* __restrict__ wt, const float* __restrict__ bias,
    const float* __restrict__ g, const float* __restrict__ bt,
    const float* __restrict__ mean, const float* __restrict__ var,
    float* __restrict__ out, int Hout, int Wout)
{
  const int c = blockIdx.y;
  const int b = blockIdx.z;
  const int p = blockIdx.x * 256 + threadIdx.x;
  const int y = p / Wout, x = p % Wout;
  const float* plane = in + ((size_t)b * NC + c) * Hin * Win;

  float a = 0.f;
  #pragma unroll
  for (int i = 0; i < 5; i++) {
    int iy = y * S - 2 + i;
    if (iy < 0 || iy >= Hin) continue;
    #pragma unroll
    for (int j = 0; j < 5; j++) {
      int ix = x * S - 2 + j;
      if (ix < 0 || ix >= Win) continue;
      a += wt[c * 25 + i * 5 + j] * plane[(size_t)iy * Win + ix];
    }
  }
  a += bias[c];
  float sc = g[c] * rsqrtf(var[c] + 1e-5f);
  a = (a - mean[c]) * sc + bt[c];
  out[((size_t)b * NC + c) * Hout * Wout + p] = a;
}

// ---------------------------------------------------------------------------
// kv prep: kvb fp32 [4][256][1024] -> kT bf16 [16][1024][32], vT bf16 [16][32][1024]
// ---------------------------------------------------------------------------
__global__ __launch_bounds__(256) void kv_prep(
    const float* __restrict__ kvb,
    short* __restrict__ kT, short* __restrict__ vT)
{
  const int t = threadIdx.x;
  const int h = blockIdx.y, b = blockIdx.z;
  const int kpos = blockIdx.x * 256 + t;
  const int bh = b * 4 + h;

  bf16x8 kr[4];
  #pragma unroll
  for (int d = 0; d < 32; d++) {
    float kvv = kvb[((size_t)b * 256 + h * 32 + d) * NKV + kpos];
    float vvv = kvb[((size_t)b * 256 + 128 + h * 32 + d) * NKV + kpos];
    kr[d >> 3][d & 7] = (short)f2bf(kvv);
    vT[(size_t)bh * 32768 + d * NKV + kpos] = (short)f2bf(vvv);
  }
  short* dst = kT + (size_t)bh * 32768 + (size_t)kpos * 32;
  #pragma unroll
  for (int i = 0; i < 4; i++)
    *(bf16x8*)(dst + i * 8) = kr[i];
}

// ---------------------------------------------------------------------------
// 32x32 MFMA flash attention, softmax fully in-register.
// S^T(key,q) = mfma32(K, Q^T): D col=q(lane&31), row=key=(r&3)+8*(r>>2)+4*hi
// P packed to bf16 via v_cvt_pk; halves exchanged with shfl_xor(32);
// O^T(d,q) = mfma32(V^T, P^T) accumulated; D row=d matches gf layout.
// ---------------------------------------------------------------------------
__global__ __launch_bounds__(256) void attn_mfma32(
    const float* __restrict__ q_local,   // [4][128][16384] fp32
    const short* __restrict__ kT,        // [16][1024][32] bf16
    const short* __restrict__ vT,        // [16][32][1024] bf16
    float* __restrict__ gf)              // [4][128][16384] fp32
{
  const int t    = threadIdx.x;
  const int w    = t >> 6;
  const int lane = t & 63;
  const int c    = lane & 31;        // q (and V-row d) index
  const int hi   = lane >> 5;
  const int b    = blockIdx.z, h = blockIdx.y;
  const int q0   = blockIdx.x * 128 + w * 32;
  const int bh   = b * 4 + h;

  const float QSCALE = 0.17677669529663689f * 1.4426950408889634f; // scale*log2e

  // Q^T B-operand fragments: lane q=c, k-depth d = hi*8+e (qf1), 16+hi*8+e (qf2)
  bf16x8 qf1, qf2;
  {
    const float* qb = q_local + ((size_t)(b * NC + h * 32 + hi * 8)) * NHW + q0 + c;
    float qv[16];
    #pragma unroll
    for (int e = 0; e < 8; e++) qv[e]     = qb[(size_t)e * NHW] * QSCALE;
    #pragma unroll
    for (int e = 0; e < 8; e++) qv[8 + e] = qb[(size_t)(16 + e) * NHW] * QSCALE;
    u32x4v q1u, q2u;
    #pragma unroll
    for (int j = 0; j < 4; j++) {
      q1u[j] = cvtpk(qv[2 * j], qv[2 * j + 1]);
      q2u[j] = cvtpk(qv[8 + 2 * j], qv[9 + 2 * j]);
    }
    qf1 = __builtin_bit_cast(bf16x8, q1u);
    qf2 = __builtin_bit_cast(bf16x8, q2u);
  }

  const short* kbh = kT + (size_t)bh * 32768;
  const short* vbh = vT + (size_t)bh * 32768;

  f32x16 oacc;
  #pragma unroll
  for (int r = 0; r < 16; r++) oacc[r] = 0.f;
  const f32x16 zf = oacc;
  float lsum = 0.f;

  // preload tile 0 fragments
  bf16x8 ka  = *(const bf16x8*)(kbh + (size_t)c * 32 + hi * 8);
  bf16x8 kb2 = *(const bf16x8*)(kbh + (size_t)c * 32 + 16 + hi * 8);
  bf16x8 va  = *(const bf16x8*)(vbh + (size_t)c * NKV + hi * 8);
  bf16x8 vb2 = *(const bf16x8*)(vbh + (size_t)c * NKV + 16 + hi * 8);

  for (int kt = 0; kt < 32; kt++) {
    const int k0n = (kt < 31) ? (kt + 1) * 32 : 0;   // clamped: always valid addr
    // prefetch next tile
    bf16x8 nka  = *(const bf16x8*)(kbh + (size_t)(k0n + c) * 32 + hi * 8);
    bf16x8 nkb  = *(const bf16x8*)(kbh + (size_t)(k0n + c) * 32 + 16 + hi * 8);
    bf16x8 nva  = *(const bf16x8*)(vbh + (size_t)c * NKV + k0n + hi * 8);
    bf16x8 nvb  = *(const bf16x8*)(vbh + (size_t)c * NKV + k0n + 16 + hi * 8);

    // S^T = K * Q^T  (exp2-domain scores)
    f32x16 s = __builtin_amdgcn_mfma_f32_32x32x16_bf16(ka,  qf1, zf, 0, 0, 0);
    s        = __builtin_amdgcn_mfma_f32_32x32x16_bf16(kb2, qf2, s,  0, 0, 0);

    float p[16];
    #pragma unroll
    for (int r = 0; r < 16; r++) p[r] = __builtin_amdgcn_exp2f(s[r]);
    // tree-sum into lsum
    {
      float s0 = (p[0] + p[1]) + (p[2] + p[3]);
      float s1 = (p[4] + p[5]) + (p[6] + p[7]);
      float s2 = (p[8] + p[9]) + (p[10] + p[11]);
      float s3 = (p[12] + p[13]) + (p[14] + p[15]);
      lsum += (s0 + s1) + (s2 + s3);
    }

    // pack P to bf16 words; W[j] = keys (base+0, base+1) per derivation
    unsigned W[8];
    #pragma unroll
    for (int j = 0; j < 8; j++) W[j] = cvtpk(p[2 * j], p[2 * j + 1]);

    // exchange across lane halves: lo half needs partner's W0/W1 (W4/W5),
    // hi half needs partner's W2/W3 (W6/W7)
    unsigned X1 = __shfl_xor(hi ? W[0] : W[2], 32);
    unsigned X2 = __shfl_xor(hi ? W[1] : W[3], 32);
    unsigned X3 = __shfl_xor(hi ? W[4] : W[6], 32);
    unsigned X4 = __shfl_xor(hi ? W[5] : W[7], 32);

    u32x4v b1u = hi ? (u32x4v){X1, X2, W[2], W[3]} : (u32x4v){W[0], W[1], X1, X2};
    u32x4v b2u = hi ? (u32x4v){X3, X4, W[6], W[7]} : (u32x4v){W[4], W[5], X3, X4};
    bf16x8 pb1 = __builtin_bit_cast(bf16x8, b1u);
    bf16x8 pb2 = __builtin_bit_cast(bf16x8, b2u);

    // O^T += V^T * P^T
    oacc = __builtin_amdgcn_mfma_f32_32x32x16_bf16(va,  pb1, oacc, 0, 0, 0);
    oacc = __builtin_amdgcn_mfma_f32_32x32x16_bf16(vb2, pb2, oacc, 0, 0, 0);

    ka = nka; kb2 = nkb; va = nva; vb2 = nvb;
  }

  lsum += __shfl_xor(lsum, 32);
  float inv = 1.f / lsum;

  float* gfb = gf + ((size_t)(b * NC + h * 32)) * NHW + q0 + c;
  #pragma unroll
  for (int r = 0; r < 16; r++) {
    int d = (r & 3) + 8 * (r >> 2) + 4 * hi;
    gfb[(size_t)d * NHW] = oacc[r] * inv;
  }
}

// ---------------------------------------------------------------------------
// lf = dw5x5(q_local) + local_b (stride 1); t = lf*sig(lf)*sig(gf)*gf
// ---------------------------------------------------------------------------
__global__ __launch_bounds__(256) void lf_fuse(
    const float* __restrict__ qloc, const float* __restrict__ gf,
    const float* __restrict__ wt, const float* __restrict__ bias,
    float* __restrict__ tout)
{
  const int c = blockIdx.y;
  const int b = blockIdx.z;
  const int p = blockIdx.x * 256 + threadIdx.x;
  const int y = p >> 7, x = p & 127;
  const float* plane = qloc + ((size_t)b * NC + c) * NHW;

  float a = 0.f;
  #pragma unroll
  for (int i = 0; i < 5; i++) {
    int iy = y - 2 + i;
    if (iy < 0 || iy >= NH) continue;
    #pragma unroll
    for (int j = 0; j < 5; j++) {
      int ix = x - 2 + j;
      if (ix < 0 || ix >= NW) continue;
      a += wt[c * 25 + i * 5 + j] * plane[iy * NW + ix];
    }
  }
  a += bias[c];
  float gv = gf[((size_t)b * NC + c) * NHW + p];
  float sl = a / (1.f + __expf(-a));
  float sg = 1.f / (1.f + __expf(-gv));
  tout[((size_t)b * NC + c) * NHW + p] = sl * sg * gv;
}

// ---------------------------------------------------------------------------
extern "C" void kernel_launch(void* const* d_in, const int* in_sizes, int n_in,
                              void* d_out, int out_size, void* d_ws, size_t ws_size,
                              hipStream_t stream) {
  const float* x       = (const float*)d_in[0];
  const float* q_w     = (const float*)d_in[1];
  const float* q_b     = (const float*)d_in[2];
  const float* kv_w    = (const float*)d_in[3];
  const float* kv_b    = (const float*)d_in[4];
  const float* local_w = (const float*)d_in[5];
  const float* local_b = (const float*)d_in[6];
  const float* mixer_w = (const float*)d_in[7];
  const float* mixer_b = (const float*)d_in[8];
  const float* p0_w    = (const float*)d_in[9];
  const float* p0_b    = (const float*)d_in[10];
  const float* bn0_g   = (const float*)d_in[11];
  const float* bn0_b   = (const float*)d_in[12];
  const float* bn0_m   = (const float*)d_in[13];
  const float* bn0_v   = (const float*)d_in[14];
  const float* lin0_w  = (const float*)d_in[15];
  const float* lin0_b  = (const float*)d_in[16];
  const float* p1_w    = (const float*)d_in[17];
  const float* p1_b    = (const float*)d_in[18];
  const float* bn1_g   = (const float*)d_in[19];
  const float* bn1_b   = (const float*)d_in[20];
  const float* bn1_m   = (const float*)d_in[21];
  const float* bn1_v   = (const float*)d_in[22];

  float* ws = (float*)d_ws;
  float* q_local = ws;                     // 8,388,608 floats
  float* gf      = ws + 8388608;           // 8,388,608
  float* tbuf    = ws + 16777216;          // 8,388,608
  float* p0      = ws + 25165824;          // 2,097,152
  float* lin0b   = ws + 27262976;          // 2,097,152
  float* p1      = ws + 29360128;          // 524,288
  float* kvb     = ws + 29884416;          // 1,048,576  (4x256x1024)
  short* kT      = (short*)(ws + 30932992);    // 524,288 shorts = 1 MB
  short* vT      = kT + 524288;                // 524,288 shorts

  // 1) q_local = pw(x, q_w) + q_b
  pw_gemm<<<dim3(NHW / 64, 1, NB), 256, 0, stream>>>(q_w, q_b, x, q_local, NHW);
  // 2) p0 = bn0(dw5x5_s2(x) + p0_b)          -> 64x64
  dw5x5_bn<2><<<dim3(4096 / 256, NC, NB), 256, 0, stream>>>(
      x, NH, NW, p0_w, p0_b, bn0_g, bn0_b, bn0_m, bn0_v, p0, 64, 64);
  // 3) lin0 = pw(p0, lin0_w) + lin0_b
  pw_gemm<<<dim3(4096 / 64, 1, NB), 256, 0, stream>>>(lin0_w, lin0_b, p0, lin0b, 4096);
  // 4) p1 = bn1(dw5x5_s2(lin0) + p1_b)       -> 32x32
  dw5x5_bn<2><<<dim3(1024 / 256, NC, NB), 256, 0, stream>>>(
      lin0b, 64, 64, p1_w, p1_b, bn1_g, bn1_b, bn1_m, bn1_v, p1, 32, 32);
  // 5) kv = pw(p1, kv_w) + kv_b   (256 out channels)
  pw_gemm<<<dim3(NKV / 64, 2, NB), 256, 0, stream>>>(kv_w, kv_b, p1, kvb, NKV);
  // 6) kv -> bf16 kT [bh][kpos][32], vT [bh][d][kpos]
  kv_prep<<<dim3(4, 4, NB), 256, 0, stream>>>(kvb, kT, vT);
  // 7) MFMA attention -> gf   (32 q per wave, 4 waves/block)
  attn_mfma32<<<dim3(128, 4, NB), 256, 0, stream>>>(q_local, kT, vT, gf);
  // 8) lf dwconv + elementwise fuse -> tbuf
  lf_fuse<<<dim3(NHW / 256, NC, NB), 256, 0, stream>>>(q_local, gf, local_w, local_b, tbuf);
  // 9) out = pw(tbuf, mixer_w) + mixer_b
  pw_gemm<<<dim3(NHW / 64, 1, NB), 256, 0, stream>>>(mixer_w, mixer_b, tbuf, (float*)d_out, NHW);
}

// Round 5
// 229.102 us; speedup vs baseline: 3.2206x; 1.4993x over previous
//
#include <hip/hip_runtime.h>
#include <hip/hip_bf16.h>
#include <math.h>

// ---------------------------------------------------------------------------
// FASA pipeline for MI355X. B=4, C=128, H=W=128, HEADS=4, dh=32, pool->32x32
// Round 5: LDS-tiled vectorized depthwise convs (lf_fuse + both pool convs).
// ---------------------------------------------------------------------------

#define NB   4
#define NC   128
#define NH   128
#define NW   128
#define NHW  16384      // 128*128
#define NKV  1024       // 32*32

typedef float    f32x4  __attribute__((ext_vector_type(4)));
typedef float    f32x16 __attribute__((ext_vector_type(16)));
typedef short    bf16x8 __attribute__((ext_vector_type(8)));
typedef unsigned u32x4v __attribute__((ext_vector_type(4)));

__device__ __forceinline__ unsigned short f2bf(float f) {
  unsigned u = __float_as_uint(f);
  u += 0x7FFF + ((u >> 16) & 1);      // round to nearest even
  return (unsigned short)(u >> 16);
}

// pack two f32 -> bf16x2 in one instr (no builtin on gfx950; T12 recipe)
__device__ __forceinline__ unsigned cvtpk(float lo, float hi) {
  unsigned r;
  asm("v_cvt_pk_bf16_f32 %0, %1, %2" : "=v"(r) : "v"(lo), "v"(hi));
  return r;
}

// ---------------------------------------------------------------------------
// Pointwise 1x1 conv as GEMM: Y[b][m0+m][pos] = bias[m] + sum_c W[m][c]*X[b][c][pos]
// ---------------------------------------------------------------------------
__global__ __launch_bounds__(256) void pw_gemm(
    const float* __restrict__ Wmat,   // [Mtot][128] row-major
    const float* __restrict__ bias,   // [Mtot]
    const float* __restrict__ X,      // [B][128][npos]
    float* __restrict__ Y,            // [B][Mtot][npos]
    int npos)
{
  __shared__ float As[32][128];   // [k][m]
  __shared__ float Bs[32][68];    // [k][n]

  const int t  = threadIdx.x;
  const int b  = blockIdx.z;
  const int m0 = blockIdx.y * 128;
  const int n0 = blockIdx.x * 64;
  const int Mtot = gridDim.y * 128;

  const float* Xb = X + (size_t)b * 128 * npos;
  float* Yb = Y + ((size_t)b * Mtot + m0) * npos;

  const int og = t >> 4;
  const int pg = t & 15;

  float acc[8][4];
  #pragma unroll
  for (int i = 0; i < 8; i++)
    #pragma unroll
    for (int j = 0; j < 4; j++) acc[i][j] = 0.f;

  const int am  = t & 127;
  const int aq0 = t >> 7;
  const int bn  = (t & 15) * 4;
  const int bc0 = t >> 4;

  for (int k0 = 0; k0 < 128; k0 += 32) {
    #pragma unroll
    for (int i = 0; i < 4; i++) {
      int q = aq0 + 2 * i;
      float4 a = *(const float4*)&Wmat[(size_t)(m0 + am) * 128 + k0 + 4 * q];
      As[4*q+0][am] = a.x; As[4*q+1][am] = a.y;
      As[4*q+2][am] = a.z; As[4*q+3][am] = a.w;
    }
    #pragma unroll
    for (int i = 0; i < 2; i++) {
      int c = bc0 + 16 * i;
      float4 v = *(const float4*)&Xb[(size_t)(k0 + c) * npos + n0 + bn];
      *(float4*)&Bs[c][bn] = v;
    }
    __syncthreads();
    #pragma unroll
    for (int k = 0; k < 32; k++) {
      float4 a0 = *(const float4*)&As[k][og * 8];
      float4 a1 = *(const float4*)&As[k][og * 8 + 4];
      float4 bv = *(const float4*)&Bs[k][pg * 4];
      float av[8] = {a0.x, a0.y, a0.z, a0.w, a1.x, a1.y, a1.z, a1.w};
      float bw[4] = {bv.x, bv.y, bv.z, bv.w};
      #pragma unroll
      for (int i = 0; i < 8; i++)
        #pragma unroll
        for (int j = 0; j < 4; j++)
          acc[i][j] += av[i] * bw[j];
    }
    __syncthreads();
  }

  #pragma unroll
  for (int i = 0; i < 8; i++) {
    int m = og * 8 + i;
    float bs = bias[m0 + m];
    float4 o;
    o.x = acc[i][0] + bs; o.y = acc[i][1] + bs;
    o.z = acc[i][2] + bs; o.w = acc[i][3] + bs;
    *(float4*)&Yb[(size_t)m * npos + n0 + pg * 4] = o;
  }
}

// ---------------------------------------------------------------------------
// LDS-tiled stride-2 depthwise 5x5 + BN.
// Block: ORPB output rows x OUTW cols of one (b,c) plane. 256 threads, 4 out/thread.
// LDS: (2*ORPB+3) rows x WLSP floats; input col i at LDS col i+4 (zero halos).
// ---------------------------------------------------------------------------
template<int INH, int INW, int OUTW, int ORPB, int WLSP>
__global__ __launch_bounds__(256) void dw5x5s2_tile(
    const float* __restrict__ in,
    const float* __restrict__ wt, const float* __restrict__ bias,
    const float* __restrict__ g, const float* __restrict__ bt,
    const float* __restrict__ mean, const float* __restrict__ var,
    float* __restrict__ out)
{
  constexpr int IR = 2 * ORPB + 3;
  constexpr int XG = OUTW / 4;
  __shared__ float Ls[IR * WLSP];

  const int t  = threadIdx.x;
  const int c  = blockIdx.y, b = blockIdx.z;
  const int y0 = blockIdx.x * ORPB;
  const float* plane = in + ((size_t)b * NC + c) * INH * INW;

  // zero all of LDS (handles row/col halos)
  for (int i = t; i < IR * WLSP / 4; i += 256)
    *(float4*)&Ls[i * 4] = (float4){0.f, 0.f, 0.f, 0.f};
  __syncthreads();

  // stage interior: rows r -> gy = 2*y0 - 2 + r
  for (int i = t; i < IR * (INW / 4); i += 256) {
    int r = i / (INW / 4), s4 = (i % (INW / 4)) * 4;
    int gy = 2 * y0 - 2 + r;
    if (gy >= 0 && gy < INH)
      *(float4*)&Ls[r * WLSP + 4 + s4] = *(const float4*)&plane[(size_t)gy * INW + s4];
  }

  float wreg[25];
  #pragma unroll
  for (int i = 0; i < 25; i++) wreg[i] = wt[c * 25 + i];
  const float sc = g[c] * rsqrtf(var[c] + 1e-5f);
  const float off = (bias[c] - mean[c]) * sc + bt[c];
  __syncthreads();

  const int row = t / XG;          // 0..ORPB-1
  const int x0  = (t % XG) * 4;    // output cols x0..x0+3
  const int r0  = 2 * row;         // first LDS row of the window

  float a[4] = {0.f, 0.f, 0.f, 0.f};
  #pragma unroll
  for (int i = 0; i < 5; i++) {
    const float* lr = &Ls[(r0 + i) * WLSP + 2 * x0];
    float4 L0 = *(const float4*)&lr[0];
    float4 L1 = *(const float4*)&lr[4];
    float4 L2 = *(const float4*)&lr[8];
    float4 L3 = *(const float4*)&lr[12];
    float rr[16] = {L0.x,L0.y,L0.z,L0.w, L1.x,L1.y,L1.z,L1.w,
                    L2.x,L2.y,L2.z,L2.w, L3.x,L3.y,L3.z,L3.w};
    #pragma unroll
    for (int j = 0; j < 5; j++) {
      float wv = wreg[i * 5 + j];
      #pragma unroll
      for (int o = 0; o < 4; o++)
        a[o] += wv * rr[2 * o + j + 2];   // in col 2*(x0+o)-2+j -> LDS rel 2o+j+2
    }
  }

  float4 ov;
  ov.x = a[0] * sc + off; ov.y = a[1] * sc + off;
  ov.z = a[2] * sc + off; ov.w = a[3] * sc + off;
  const int OH = INH / 2;
  *(float4*)&out[((size_t)b * NC + c) * OH * OUTW + (size_t)(y0 + row) * OUTW + x0] = ov;
}

// ---------------------------------------------------------------------------
// kv prep: kvb fp32 [4][256][1024] -> kT bf16 [16][1024][32], vT bf16 [16][32][1024]
// ---------------------------------------------------------------------------
__global__ __launch_bounds__(256) void kv_prep(
    const float* __restrict__ kvb,
    short* __restrict__ kT, short* __restrict__ vT)
{
  const int t = threadIdx.x;
  const int h = blockIdx.y, b = blockIdx.z;
  const int kpos = blockIdx.x * 256 + t;
  const int bh = b * 4 + h;

  bf16x8 kr[4];
  #pragma unroll
  for (int d = 0; d < 32; d++) {
    float kvv = kvb[((size_t)b * 256 + h * 32 + d) * NKV + kpos];
    float vvv = kvb[((size_t)b * 256 + 128 + h * 32 + d) * NKV + kpos];
    kr[d >> 3][d & 7] = (short)f2bf(kvv);
    vT[(size_t)bh * 32768 + d * NKV + kpos] = (short)f2bf(vvv);
  }
  short* dst = kT + (size_t)bh * 32768 + (size_t)kpos * 32;
  #pragma unroll
  for (int i = 0; i < 4; i++)
    *(bf16x8*)(dst + i * 8) = kr[i];
}

// ---------------------------------------------------------------------------
// 32x32 MFMA flash attention, softmax fully in-register.
// ---------------------------------------------------------------------------
__global__ __launch_bounds__(256) void attn_mfma32(
    const float* __restrict__ q_local,   // [4][128][16384] fp32
    const short* __restrict__ kT,        // [16][1024][32] bf16
    const short* __restrict__ vT,        // [16][32][1024] bf16
    float* __restrict__ gf)              // [4][128][16384] fp32
{
  const int t    = threadIdx.x;
  const int w    = t >> 6;
  const int lane = t & 63;
  const int c    = lane & 31;
  const int hi   = lane >> 5;
  const int b    = blockIdx.z, h = blockIdx.y;
  const int q0   = blockIdx.x * 128 + w * 32;
  const int bh   = b * 4 + h;

  const float QSCALE = 0.17677669529663689f * 1.4426950408889634f; // scale*log2e

  bf16x8 qf1, qf2;
  {
    const float* qb = q_local + ((size_t)(b * NC + h * 32 + hi * 8)) * NHW + q0 + c;
    float qv[16];
    #pragma unroll
    for (int e = 0; e < 8; e++) qv[e]     = qb[(size_t)e * NHW] * QSCALE;
    #pragma unroll
    for (int e = 0; e < 8; e++) qv[8 + e] = qb[(size_t)(16 + e) * NHW] * QSCALE;
    u32x4v q1u, q2u;
    #pragma unroll
    for (int j = 0; j < 4; j++) {
      q1u[j] = cvtpk(qv[2 * j], qv[2 * j + 1]);
      q2u[j] = cvtpk(qv[8 + 2 * j], qv[9 + 2 * j]);
    }
    qf1 = __builtin_bit_cast(bf16x8, q1u);
    qf2 = __builtin_bit_cast(bf16x8, q2u);
  }

  const short* kbh = kT + (size_t)bh * 32768;
  const short* vbh = vT + (size_t)bh * 32768;

  f32x16 oacc;
  #pragma unroll
  for (int r = 0; r < 16; r++) oacc[r] = 0.f;
  const f32x16 zf = oacc;
  float lsum = 0.f;

  bf16x8 ka  = *(const bf16x8*)(kbh + (size_t)c * 32 + hi * 8);
  bf16x8 kb2 = *(const bf16x8*)(kbh + (size_t)c * 32 + 16 + hi * 8);
  bf16x8 va  = *(const bf16x8*)(vbh + (size_t)c * NKV + hi * 8);
  bf16x8 vb2 = *(const bf16x8*)(vbh + (size_t)c * NKV + 16 + hi * 8);

  for (int kt = 0; kt < 32; kt++) {
    const int k0n = (kt < 31) ? (kt + 1) * 32 : 0;
    bf16x8 nka  = *(const bf16x8*)(kbh + (size_t)(k0n + c) * 32 + hi * 8);
    bf16x8 nkb  = *(const bf16x8*)(kbh + (size_t)(k0n + c) * 32 + 16 + hi * 8);
    bf16x8 nva  = *(const bf16x8*)(vbh + (size_t)c * NKV + k0n + hi * 8);
    bf16x8 nvb  = *(const bf16x8*)(vbh + (size_t)c * NKV + k0n + 16 + hi * 8);

    f32x16 s = __builtin_amdgcn_mfma_f32_32x32x16_bf16(ka,  qf1, zf, 0, 0, 0);
    s        = __builtin_amdgcn_mfma_f32_32x32x16_bf16(kb2, qf2, s,  0, 0, 0);

    float p[16];
    #pragma unroll
    for (int r = 0; r < 16; r++) p[r] = __builtin_amdgcn_exp2f(s[r]);
    {
      float s0 = (p[0] + p[1]) + (p[2] + p[3]);
      float s1 = (p[4] + p[5]) + (p[6] + p[7]);
      float s2 = (p[8] + p[9]) + (p[10] + p[11]);
      float s3 = (p[12] + p[13]) + (p[14] + p[15]);
      lsum += (s0 + s1) + (s2 + s3);
    }

    unsigned W[8];
    #pragma unroll
    for (int j = 0; j < 8; j++) W[j] = cvtpk(p[2 * j], p[2 * j + 1]);

    unsigned X1 = __shfl_xor(hi ? W[0] : W[2], 32);
    unsigned X2 = __shfl_xor(hi ? W[1] : W[3], 32);
    unsigned X3 = __shfl_xor(hi ? W[4] : W[6], 32);
    unsigned X4 = __shfl_xor(hi ? W[5] : W[7], 32);

    u32x4v b1u = hi ? (u32x4v){X1, X2, W[2], W[3]} : (u32x4v){W[0], W[1], X1, X2};
    u32x4v b2u = hi ? (u32x4v){X3, X4, W[6], W[7]} : (u32x4v){W[4], W[5], X3, X4};
    bf16x8 pb1 = __builtin_bit_cast(bf16x8, b1u);
    bf16x8 pb2 = __builtin_bit_cast(bf16x8, b2u);

    oacc = __builtin_amdgcn_mfma_f32_32x32x16_bf16(va,  pb1, oacc, 0, 0, 0);
    oacc = __builtin_amdgcn_mfma_f32_32x32x16_bf16(vb2, pb2, oacc, 0, 0, 0);

    ka = nka; kb2 = nkb; va = nva; vb2 = nvb;
  }

  lsum += __shfl_xor(lsum, 32);
  float inv = 1.f / lsum;

  float* gfb = gf + ((size_t)(b * NC + h * 32)) * NHW + q0 + c;
  #pragma unroll
  for (int r = 0; r < 16; r++) {
    int d = (r & 3) + 8 * (r >> 2) + 4 * hi;
    gfb[(size_t)d * NHW] = oacc[r] * inv;
  }
}

// ---------------------------------------------------------------------------
// LDS-tiled lf_fuse: lf = dw5x5_s1(q_local)+local_b; t = lf*sig(lf)*sig(gf)*gf
// Block: 8 output rows x 128 cols of one (b,c) plane; 4 outputs/thread.
// LDS: 12 rows x 140; input col i at LDS col i+4.
// ---------------------------------------------------------------------------
__global__ __launch_bounds__(256) void lf_fuse_tile(
    const float* __restrict__ qloc, const float* __restrict__ gf,
    const float* __restrict__ wt, const float* __restrict__ bias,
    float* __restrict__ tout)
{
  __shared__ float Ls[12 * 140];

  const int t  = threadIdx.x;
  const int c  = blockIdx.y, b = blockIdx.z;
  const int y0 = blockIdx.x * 8;
  const float* plane = qloc + ((size_t)b * NC + c) * NHW;

  for (int i = t; i < 12 * 140 / 4; i += 256)
    *(float4*)&Ls[i * 4] = (float4){0.f, 0.f, 0.f, 0.f};
  __syncthreads();

  for (int i = t; i < 12 * 32; i += 256) {
    int r = i >> 5, s4 = (i & 31) * 4;
    int gy = y0 - 2 + r;
    if (gy >= 0 && gy < NH)
      *(float4*)&Ls[r * 140 + 4 + s4] = *(const float4*)&plane[(size_t)gy * NW + s4];
  }

  float wreg[25];
  #pragma unroll
  for (int i = 0; i < 25; i++) wreg[i] = wt[c * 25 + i];
  const float bs = bias[c];
  __syncthreads();

  const int row = t >> 5;          // 0..7
  const int x0  = (t & 31) * 4;    // 0..124

  float a[4] = {bs, bs, bs, bs};
  #pragma unroll
  for (int i = 0; i < 5; i++) {
    const float* lr = &Ls[(row + i) * 140 + x0];
    float4 L0 = *(const float4*)&lr[0];
    float4 L1 = *(const float4*)&lr[4];
    float4 L2 = *(const float4*)&lr[8];
    float rr[12] = {L0.x,L0.y,L0.z,L0.w, L1.x,L1.y,L1.z,L1.w,
                    L2.x,L2.y,L2.z,L2.w};
    #pragma unroll
    for (int j = 0; j < 5; j++) {
      float wv = wreg[i * 5 + j];
      #pragma unroll
      for (int o = 0; o < 4; o++)
        a[o] += wv * rr[o + j + 2];   // in col x0+o-2+j -> LDS rel o+j+2
    }
  }

  size_t base = ((size_t)b * NC + c) * NHW + (size_t)(y0 + row) * NW + x0;
  float4 gv4 = *(const float4*)&gf[base];
  float gvv[4] = {gv4.x, gv4.y, gv4.z, gv4.w};
  float4 ov;
  float* op = (float*)&ov;
  #pragma unroll
  for (int k = 0; k < 4; k++) {
    float sl = a[k] / (1.f + __expf(-a[k]));
    float sg = 1.f / (1.f + __expf(-gvv[k]));
    op[k] = sl * sg * gvv[k];
  }
  *(float4*)&tout[base] = ov;
}

// ---------------------------------------------------------------------------
extern "C" void kernel_launch(void* const* d_in, const int* in_sizes, int n_in,
                              void* d_out, int out_size, void* d_ws, size_t ws_size,
                              hipStream_t stream) {
  const float* x       = (const float*)d_in[0];
  const float* q_w     = (const float*)d_in[1];
  const float* q_b     = (const float*)d_in[2];
  const float* kv_w    = (const float*)d_in[3];
  const float* kv_b    = (const float*)d_in[4];
  const float* local_w = (const float*)d_in[5];
  const float* local_b = (const float*)d_in[6];
  const float* mixer_w = (const float*)d_in[7];
  const float* mixer_b = (const float*)d_in[8];
  const float* p0_w    = (const float*)d_in[9];
  const float* p0_b    = (const float*)d_in[10];
  const float* bn0_g   = (const float*)d_in[11];
  const float* bn0_b   = (const float*)d_in[12];
  const float* bn0_m   = (const float*)d_in[13];
  const float* bn0_v   = (const float*)d_in[14];
  const float* lin0_w  = (const float*)d_in[15];
  const float* lin0_b  = (const float*)d_in[16];
  const float* p1_w    = (const float*)d_in[17];
  const float* p1_b    = (const float*)d_in[18];
  const float* bn1_g   = (const float*)d_in[19];
  const float* bn1_b   = (const float*)d_in[20];
  const float* bn1_m   = (const float*)d_in[21];
  const float* bn1_v   = (const float*)d_in[22];

  float* ws = (float*)d_ws;
  float* q_local = ws;                     // 8,388,608 floats
  float* gf      = ws + 8388608;           // 8,388,608
  float* tbuf    = ws + 16777216;          // 8,388,608
  float* p0      = ws + 25165824;          // 2,097,152
  float* lin0b   = ws + 27262976;          // 2,097,152
  float* p1      = ws + 29360128;          // 524,288
  float* kvb     = ws + 29884416;          // 1,048,576  (4x256x1024)
  short* kT      = (short*)(ws + 30932992);    // 524,288 shorts = 1 MB
  short* vT      = kT + 524288;                // 524,288 shorts

  // 1) q_local = pw(x, q_w) + q_b
  pw_gemm<<<dim3(NHW / 64, 1, NB), 256, 0, stream>>>(q_w, q_b, x, q_local, NHW);
  // 2) p0 = bn0(dw5x5_s2(x) + p0_b)          -> 64x64
  dw5x5s2_tile<128, 128, 64, 16, 140><<<dim3(4, NC, NB), 256, 0, stream>>>(
      x, p0_w, p0_b, bn0_g, bn0_b, bn0_m, bn0_v, p0);
  // 3) lin0 = pw(p0, lin0_w) + lin0_b
  pw_gemm<<<dim3(4096 / 64, 1, NB), 256, 0, stream>>>(lin0_w, lin0_b, p0, lin0b, 4096);
  // 4) p1 = bn1(dw5x5_s2(lin0) + p1_b)       -> 32x32
  dw5x5s2_tile<64, 64, 32, 32, 76><<<dim3(1, NC, NB), 256, 0, stream>>>(
      lin0b, p1_w, p1_b, bn1_g, bn1_b, bn1_m, bn1_v, p1);
  // 5) kv = pw(p1, kv_w) + kv_b   (256 out channels)
  pw_gemm<<<dim3(NKV / 64, 2, NB), 256, 0, stream>>>(kv_w, kv_b, p1, kvb, NKV);
  // 6) kv -> bf16 kT [bh][kpos][32], vT [bh][d][kpos]
  kv_prep<<<dim3(4, 4, NB), 256, 0, stream>>>(kvb, kT, vT);
  // 7) MFMA attention -> gf   (32 q per wave, 4 waves/block)
  attn_mfma32<<<dim3(128, 4, NB), 256, 0, stream>>>(q_local, kT, vT, gf);
  // 8) lf dwconv + elementwise fuse -> tbuf
  lf_fuse_tile<<<dim3(16, NC, NB), 256, 0, stream>>>(q_local, gf, local_w, local_b, tbuf);
  // 9) out = pw(tbuf, mixer_w) + mixer_b
  pw_gemm<<<dim3(NHW / 64, 1, NB), 256, 0, stream>>>(mixer_w, mixer_b, tbuf, (float*)d_out, NHW);
}

// Round 6
// 198.810 us; speedup vs baseline: 3.7113x; 1.1524x over previous
//
#include <hip/hip_runtime.h>
#include <hip/hip_bf16.h>
#include <math.h>

// ---------------------------------------------------------------------------
// FASA pipeline for MI355X. B=4, C=128, H=W=128, HEADS=4, dh=32, pool->32x32
// Round 6: bf16 MFMA pointwise GEMMs; permlane32_swap softmax exchange.
// ---------------------------------------------------------------------------

#define NB   4
#define NC   128
#define NH   128
#define NW   128
#define NHW  16384      // 128*128
#define NKV  1024       // 32*32

typedef float    f32x4  __attribute__((ext_vector_type(4)));
typedef float    f32x16 __attribute__((ext_vector_type(16)));
typedef short    bf16x8 __attribute__((ext_vector_type(8)));
typedef unsigned u32x4v __attribute__((ext_vector_type(4)));

__device__ __forceinline__ unsigned short f2bf(float f) {
  unsigned u = __float_as_uint(f);
  u += 0x7FFF + ((u >> 16) & 1);      // round to nearest even
  return (unsigned short)(u >> 16);
}

// pack two f32 -> bf16x2 in one instr (no builtin on gfx950; T12 recipe)
__device__ __forceinline__ unsigned cvtpk(float lo, float hi) {
  unsigned r;
  asm("v_cvt_pk_bf16_f32 %0, %1, %2" : "=v"(r) : "v"(lo), "v"(hi));
  return r;
}

// ---------------------------------------------------------------------------
// MFMA pointwise 1x1 conv: Y[b][m][n] = bias[m] + sum_c W[m][c] X[b][c][n]
// K=128. Block: 128 M x 128 N, 256 thr = 4 waves; wave w owns N cols
// w*32..w*32+31 and loops 4 M-groups of 32. W staged to LDS bf16; X converted
// in-register. D layout: row=(r&3)+8*(r>>2)+4*hi, col=lane&31 (verified in attn).
// ---------------------------------------------------------------------------
__global__ __launch_bounds__(256) void pw_gemm_mfma(
    const float* __restrict__ Wmat,   // [Mtot][128]
    const float* __restrict__ bias,   // [Mtot]
    const float* __restrict__ X,      // [B][128][npos] fp32
    float* __restrict__ Y,            // [B][Mtot][npos] fp32
    int npos)
{
  __shared__ short Wlds[128 * 136];   // [m][c] bf16, row stride 136 (272B, 16B-aligned)

  const int t  = threadIdx.x;
  const int w    = t >> 6;
  const int lane = t & 63;
  const int nl   = lane & 31;
  const int hi   = lane >> 5;
  const int b  = blockIdx.z;
  const int m0 = blockIdx.y * 128;
  const int n0 = blockIdx.x * 128;
  const int Mtot = gridDim.y * 128;

  // stage W[m0..m0+127][0..127] -> bf16 LDS
  for (int i = t; i < 128 * 32; i += 256) {
    int row = i >> 5, c4 = (i & 31) * 4;
    float4 wv = *(const float4*)&Wmat[(size_t)(m0 + row) * 128 + c4];
    uint2 pk; pk.x = cvtpk(wv.x, wv.y); pk.y = cvtpk(wv.z, wv.w);
    *(uint2*)&Wlds[row * 136 + c4] = pk;
  }
  __syncthreads();

  const float* Xb = X + (size_t)b * 128 * npos + n0 + w * 32 + nl;

  f32x16 acc[4];
  #pragma unroll
  for (int mg = 0; mg < 4; mg++)
    #pragma unroll
    for (int r = 0; r < 16; r++) acc[mg][r] = 0.f;

  #pragma unroll
  for (int s = 0; s < 8; s++) {           // k-step of 16: k = s*16 + hi*8 + e
    const float* xp = Xb + (size_t)(s * 16 + hi * 8) * npos;
    float xv[8];
    #pragma unroll
    for (int e = 0; e < 8; e++) xv[e] = xp[(size_t)e * npos];
    u32x4v bu;
    #pragma unroll
    for (int j = 0; j < 4; j++) bu[j] = cvtpk(xv[2 * j], xv[2 * j + 1]);
    bf16x8 bfrag = __builtin_bit_cast(bf16x8, bu);

    #pragma unroll
    for (int mg = 0; mg < 4; mg++) {
      bf16x8 afrag = *(const bf16x8*)&Wlds[(mg * 32 + nl) * 136 + s * 16 + hi * 8];
      acc[mg] = __builtin_amdgcn_mfma_f32_32x32x16_bf16(afrag, bfrag, acc[mg], 0, 0, 0);
    }
  }

  float* Yb = Y + ((size_t)b * Mtot + m0) * npos + n0 + w * 32 + nl;
  #pragma unroll
  for (int mg = 0; mg < 4; mg++)
    #pragma unroll
    for (int r = 0; r < 16; r++) {
      int drow = mg * 32 + (r & 3) + 8 * (r >> 2) + 4 * hi;
      Yb[(size_t)drow * npos] = acc[mg][r] + bias[m0 + drow];
    }
}

// ---------------------------------------------------------------------------
// LDS-tiled stride-2 depthwise 5x5 + BN.
// ---------------------------------------------------------------------------
template<int INH, int INW, int OUTW, int ORPB, int WLSP>
__global__ __launch_bounds__(256) void dw5x5s2_tile(
    const float* __restrict__ in,
    const float* __restrict__ wt, const float* __restrict__ bias,
    const float* __restrict__ g, const float* __restrict__ bt,
    const float* __restrict__ mean, const float* __restrict__ var,
    float* __restrict__ out)
{
  constexpr int IR = 2 * ORPB + 3;
  constexpr int XG = OUTW / 4;
  __shared__ float Ls[IR * WLSP];

  const int t  = threadIdx.x;
  const int c  = blockIdx.y, b = blockIdx.z;
  const int y0 = blockIdx.x * ORPB;
  const float* plane = in + ((size_t)b * NC + c) * INH * INW;

  for (int i = t; i < IR * WLSP / 4; i += 256)
    *(float4*)&Ls[i * 4] = (float4){0.f, 0.f, 0.f, 0.f};
  __syncthreads();

  for (int i = t; i < IR * (INW / 4); i += 256) {
    int r = i / (INW / 4), s4 = (i % (INW / 4)) * 4;
    int gy = 2 * y0 - 2 + r;
    if (gy >= 0 && gy < INH)
      *(float4*)&Ls[r * WLSP + 4 + s4] = *(const float4*)&plane[(size_t)gy * INW + s4];
  }

  float wreg[25];
  #pragma unroll
  for (int i = 0; i < 25; i++) wreg[i] = wt[c * 25 + i];
  const float sc = g[c] * rsqrtf(var[c] + 1e-5f);
  const float off = (bias[c] - mean[c]) * sc + bt[c];
  __syncthreads();

  const int row = t / XG;
  const int x0  = (t % XG) * 4;
  const int r0  = 2 * row;

  float a[4] = {0.f, 0.f, 0.f, 0.f};
  #pragma unroll
  for (int i = 0; i < 5; i++) {
    const float* lr = &Ls[(r0 + i) * WLSP + 2 * x0];
    float4 L0 = *(const float4*)&lr[0];
    float4 L1 = *(const float4*)&lr[4];
    float4 L2 = *(const float4*)&lr[8];
    float4 L3 = *(const float4*)&lr[12];
    float rr[16] = {L0.x,L0.y,L0.z,L0.w, L1.x,L1.y,L1.z,L1.w,
                    L2.x,L2.y,L2.z,L2.w, L3.x,L3.y,L3.z,L3.w};
    #pragma unroll
    for (int j = 0; j < 5; j++) {
      float wv = wreg[i * 5 + j];
      #pragma unroll
      for (int o = 0; o < 4; o++)
        a[o] += wv * rr[2 * o + j + 2];
    }
  }

  float4 ov;
  ov.x = a[0] * sc + off; ov.y = a[1] * sc + off;
  ov.z = a[2] * sc + off; ov.w = a[3] * sc + off;
  const int OH = INH / 2;
  *(float4*)&out[((size_t)b * NC + c) * OH * OUTW + (size_t)(y0 + row) * OUTW + x0] = ov;
}

// ---------------------------------------------------------------------------
// kv prep: kvb fp32 [4][256][1024] -> kT bf16 [16][1024][32], vT bf16 [16][32][1024]
// ---------------------------------------------------------------------------
__global__ __launch_bounds__(256) void kv_prep(
    const float* __restrict__ kvb,
    short* __restrict__ kT, short* __restrict__ vT)
{
  const int t = threadIdx.x;
  const int h = blockIdx.y, b = blockIdx.z;
  const int kpos = blockIdx.x * 256 + t;
  const int bh = b * 4 + h;

  bf16x8 kr[4];
  #pragma unroll
  for (int d = 0; d < 32; d++) {
    float kvv = kvb[((size_t)b * 256 + h * 32 + d) * NKV + kpos];
    float vvv = kvb[((size_t)b * 256 + 128 + h * 32 + d) * NKV + kpos];
    kr[d >> 3][d & 7] = (short)f2bf(kvv);
    vT[(size_t)bh * 32768 + d * NKV + kpos] = (short)f2bf(vvv);
  }
  short* dst = kT + (size_t)bh * 32768 + (size_t)kpos * 32;
  #pragma unroll
  for (int i = 0; i < 4; i++)
    *(bf16x8*)(dst + i * 8) = kr[i];
}

// ---------------------------------------------------------------------------
// 32x32 MFMA flash attention, softmax fully in-register (permlane32_swap).
// ---------------------------------------------------------------------------
__global__ __launch_bounds__(256) void attn_mfma32(
    const float* __restrict__ q_local,   // [4][128][16384] fp32
    const short* __restrict__ kT,        // [16][1024][32] bf16
    const short* __restrict__ vT,        // [16][32][1024] bf16
    float* __restrict__ gf)              // [4][128][16384] fp32
{
  const int t    = threadIdx.x;
  const int w    = t >> 6;
  const int lane = t & 63;
  const int c    = lane & 31;
  const int hi   = lane >> 5;
  const int b    = blockIdx.z, h = blockIdx.y;
  const int q0   = blockIdx.x * 128 + w * 32;
  const int bh   = b * 4 + h;

  const float QSCALE = 0.17677669529663689f * 1.4426950408889634f; // scale*log2e

  bf16x8 qf1, qf2;
  {
    const float* qb = q_local + ((size_t)(b * NC + h * 32 + hi * 8)) * NHW + q0 + c;
    float qv[16];
    #pragma unroll
    for (int e = 0; e < 8; e++) qv[e]     = qb[(size_t)e * NHW] * QSCALE;
    #pragma unroll
    for (int e = 0; e < 8; e++) qv[8 + e] = qb[(size_t)(16 + e) * NHW] * QSCALE;
    u32x4v q1u, q2u;
    #pragma unroll
    for (int j = 0; j < 4; j++) {
      q1u[j] = cvtpk(qv[2 * j], qv[2 * j + 1]);
      q2u[j] = cvtpk(qv[8 + 2 * j], qv[9 + 2 * j]);
    }
    qf1 = __builtin_bit_cast(bf16x8, q1u);
    qf2 = __builtin_bit_cast(bf16x8, q2u);
  }

  const short* kbh = kT + (size_t)bh * 32768;
  const short* vbh = vT + (size_t)bh * 32768;

  f32x16 oacc;
  #pragma unroll
  for (int r = 0; r < 16; r++) oacc[r] = 0.f;
  const f32x16 zf = oacc;
  float lsum = 0.f;

  bf16x8 ka  = *(const bf16x8*)(kbh + (size_t)c * 32 + hi * 8);
  bf16x8 kb2 = *(const bf16x8*)(kbh + (size_t)c * 32 + 16 + hi * 8);
  bf16x8 va  = *(const bf16x8*)(vbh + (size_t)c * NKV + hi * 8);
  bf16x8 vb2 = *(const bf16x8*)(vbh + (size_t)c * NKV + 16 + hi * 8);

  for (int kt = 0; kt < 32; kt++) {
    const int k0n = (kt < 31) ? (kt + 1) * 32 : 0;
    bf16x8 nka  = *(const bf16x8*)(kbh + (size_t)(k0n + c) * 32 + hi * 8);
    bf16x8 nkb  = *(const bf16x8*)(kbh + (size_t)(k0n + c) * 32 + 16 + hi * 8);
    bf16x8 nva  = *(const bf16x8*)(vbh + (size_t)c * NKV + k0n + hi * 8);
    bf16x8 nvb  = *(const bf16x8*)(vbh + (size_t)c * NKV + k0n + 16 + hi * 8);

    f32x16 s = __builtin_amdgcn_mfma_f32_32x32x16_bf16(ka,  qf1, zf, 0, 0, 0);
    s        = __builtin_amdgcn_mfma_f32_32x32x16_bf16(kb2, qf2, s,  0, 0, 0);

    float p[16];
    #pragma unroll
    for (int r = 0; r < 16; r++) p[r] = __builtin_amdgcn_exp2f(s[r]);
    {
      float s0 = (p[0] + p[1]) + (p[2] + p[3]);
      float s1 = (p[4] + p[5]) + (p[6] + p[7]);
      float s2 = (p[8] + p[9]) + (p[10] + p[11]);
      float s3 = (p[12] + p[13]) + (p[14] + p[15]);
      lsum += (s0 + s1) + (s2 + s3);
    }

    // pack P to bf16 words: W[j] holds keys (2j, 2j+1) of this lane's half
    unsigned a0 = cvtpk(p[0],  p[1]);
    unsigned a1 = cvtpk(p[2],  p[3]);
    unsigned a2 = cvtpk(p[4],  p[5]);
    unsigned a3 = cvtpk(p[6],  p[7]);
    unsigned a4 = cvtpk(p[8],  p[9]);
    unsigned a5 = cvtpk(p[10], p[11]);
    unsigned a6 = cvtpk(p[12], p[13]);
    unsigned a7 = cvtpk(p[14], p[15]);

    // half-swap: vdst upper 32 lanes <-> vsrc lower 32 lanes.
    // After swap(a0,a2): a0 = {lo:own W0, hi:lo-partner W2}, a2 = {lo:hi-partner W0, hi:own W2}
    asm("v_permlane32_swap_b32 %0, %1" : "+v"(a0), "+v"(a2));
    asm("v_permlane32_swap_b32 %0, %1" : "+v"(a1), "+v"(a3));
    asm("v_permlane32_swap_b32 %0, %1" : "+v"(a4), "+v"(a6));
    asm("v_permlane32_swap_b32 %0, %1" : "+v"(a5), "+v"(a7));

    u32x4v b1u = {a0, a1, a2, a3};
    u32x4v b2u = {a4, a5, a6, a7};
    bf16x8 pb1 = __builtin_bit_cast(bf16x8, b1u);
    bf16x8 pb2 = __builtin_bit_cast(bf16x8, b2u);

    oacc = __builtin_amdgcn_mfma_f32_32x32x16_bf16(va,  pb1, oacc, 0, 0, 0);
    oacc = __builtin_amdgcn_mfma_f32_32x32x16_bf16(vb2, pb2, oacc, 0, 0, 0);

    ka = nka; kb2 = nkb; va = nva; vb2 = nvb;
  }

  lsum += __shfl_xor(lsum, 32);
  float inv = 1.f / lsum;

  float* gfb = gf + ((size_t)(b * NC + h * 32)) * NHW + q0 + c;
  #pragma unroll
  for (int r = 0; r < 16; r++) {
    int d = (r & 3) + 8 * (r >> 2) + 4 * hi;
    gfb[(size_t)d * NHW] = oacc[r] * inv;
  }
}

// ---------------------------------------------------------------------------
// LDS-tiled lf_fuse: lf = dw5x5_s1(q_local)+local_b; t = lf*sig(lf)*sig(gf)*gf
// ---------------------------------------------------------------------------
__global__ __launch_bounds__(256) void lf_fuse_tile(
    const float* __restrict__ qloc, const float* __restrict__ gf,
    const float* __restrict__ wt, const float* __restrict__ bias,
    float* __restrict__ tout)
{
  __shared__ float Ls[12 * 140];

  const int t  = threadIdx.x;
  const int c  = blockIdx.y, b = blockIdx.z;
  const int y0 = blockIdx.x * 8;
  const float* plane = qloc + ((size_t)b * NC + c) * NHW;

  for (int i = t; i < 12 * 140 / 4; i += 256)
    *(float4*)&Ls[i * 4] = (float4){0.f, 0.f, 0.f, 0.f};
  __syncthreads();

  for (int i = t; i < 12 * 32; i += 256) {
    int r = i >> 5, s4 = (i & 31) * 4;
    int gy = y0 - 2 + r;
    if (gy >= 0 && gy < NH)
      *(float4*)&Ls[r * 140 + 4 + s4] = *(const float4*)&plane[(size_t)gy * NW + s4];
  }

  float wreg[25];
  #pragma unroll
  for (int i = 0; i < 25; i++) wreg[i] = wt[c * 25 + i];
  const float bs = bias[c];
  __syncthreads();

  const int row = t >> 5;
  const int x0  = (t & 31) * 4;

  float a[4] = {bs, bs, bs, bs};
  #pragma unroll
  for (int i = 0; i < 5; i++) {
    const float* lr = &Ls[(row + i) * 140 + x0];
    float4 L0 = *(const float4*)&lr[0];
    float4 L1 = *(const float4*)&lr[4];
    float4 L2 = *(const float4*)&lr[8];
    float rr[12] = {L0.x,L0.y,L0.z,L0.w, L1.x,L1.y,L1.z,L1.w,
                    L2.x,L2.y,L2.z,L2.w};
    #pragma unroll
    for (int j = 0; j < 5; j++) {
      float wv = wreg[i * 5 + j];
      #pragma unroll
      for (int o = 0; o < 4; o++)
        a[o] += wv * rr[o + j + 2];
    }
  }

  size_t base = ((size_t)b * NC + c) * NHW + (size_t)(y0 + row) * NW + x0;
  float4 gv4 = *(const float4*)&gf[base];
  float gvv[4] = {gv4.x, gv4.y, gv4.z, gv4.w};
  float4 ov;
  float* op = (float*)&ov;
  #pragma unroll
  for (int k = 0; k < 4; k++) {
    float sl = a[k] / (1.f + __expf(-a[k]));
    float sg = 1.f / (1.f + __expf(-gvv[k]));
    op[k] = sl * sg * gvv[k];
  }
  *(float4*)&tout[base] = ov;
}

// ---------------------------------------------------------------------------
extern "C" void kernel_launch(void* const* d_in, const int* in_sizes, int n_in,
                              void* d_out, int out_size, void* d_ws, size_t ws_size,
                              hipStream_t stream) {
  const float* x       = (const float*)d_in[0];
  const float* q_w     = (const float*)d_in[1];
  const float* q_b     = (const float*)d_in[2];
  const float* kv_w    = (const float*)d_in[3];
  const float* kv_b    = (const float*)d_in[4];
  const float* local_w = (const float*)d_in[5];
  const float* local_b = (const float*)d_in[6];
  const float* mixer_w = (const float*)d_in[7];
  const float* mixer_b = (const float*)d_in[8];
  const float* p0_w    = (const float*)d_in[9];
  const float* p0_b    = (const float*)d_in[10];
  const float* bn0_g   = (const float*)d_in[11];
  const float* bn0_b   = (const float*)d_in[12];
  const float* bn0_m   = (const float*)d_in[13];
  const float* bn0_v   = (const float*)d_in[14];
  const float* lin0_w  = (const float*)d_in[15];
  const float* lin0_b  = (const float*)d_in[16];
  const float* p1_w    = (const float*)d_in[17];
  const float* p1_b    = (const float*)d_in[18];
  const float* bn1_g   = (const float*)d_in[19];
  const float* bn1_b   = (const float*)d_in[20];
  const float* bn1_m   = (const float*)d_in[21];
  const float* bn1_v   = (const float*)d_in[22];

  float* ws = (float*)d_ws;
  float* q_local = ws;                     // 8,388,608 floats
  float* gf      = ws + 8388608;           // 8,388,608
  float* tbuf    = ws + 16777216;          // 8,388,608
  float* p0      = ws + 25165824;          // 2,097,152
  float* lin0b   = ws + 27262976;          // 2,097,152
  float* p1      = ws + 29360128;          // 524,288
  float* kvb     = ws + 29884416;          // 1,048,576  (4x256x1024)
  short* kT      = (short*)(ws + 30932992);    // 524,288 shorts = 1 MB
  short* vT      = kT + 524288;                // 524,288 shorts

  // 1) q_local = pw(x, q_w) + q_b
  pw_gemm_mfma<<<dim3(NHW / 128, 1, NB), 256, 0, stream>>>(q_w, q_b, x, q_local, NHW);
  // 2) p0 = bn0(dw5x5_s2(x) + p0_b)          -> 64x64
  dw5x5s2_tile<128, 128, 64, 16, 140><<<dim3(4, NC, NB), 256, 0, stream>>>(
      x, p0_w, p0_b, bn0_g, bn0_b, bn0_m, bn0_v, p0);
  // 3) lin0 = pw(p0, lin0_w) + lin0_b
  pw_gemm_mfma<<<dim3(4096 / 128, 1, NB), 256, 0, stream>>>(lin0_w, lin0_b, p0, lin0b, 4096);
  // 4) p1 = bn1(dw5x5_s2(lin0) + p1_b)       -> 32x32
  dw5x5s2_tile<64, 64, 32, 32, 76><<<dim3(1, NC, NB), 256, 0, stream>>>(
      lin0b, p1_w, p1_b, bn1_g, bn1_b, bn1_m, bn1_v, p1);
  // 5) kv = pw(p1, kv_w) + kv_b   (256 out channels)
  pw_gemm_mfma<<<dim3(NKV / 128, 2, NB), 256, 0, stream>>>(kv_w, kv_b, p1, kvb, NKV);
  // 6) kv -> bf16 kT [bh][kpos][32], vT [bh][d][kpos]
  kv_prep<<<dim3(4, 4, NB), 256, 0, stream>>>(kvb, kT, vT);
  // 7) MFMA attention -> gf   (32 q per wave, 4 waves/block)
  attn_mfma32<<<dim3(128, 4, NB), 256, 0, stream>>>(q_local, kT, vT, gf);
  // 8) lf dwconv + elementwise fuse -> tbuf
  lf_fuse_tile<<<dim3(16, NC, NB), 256, 0, stream>>>(q_local, gf, local_w, local_b, tbuf);
  // 9) out = pw(tbuf, mixer_w) + mixer_b
  pw_gemm_mfma<<<dim3(NHW / 128, 1, NB), 256, 0, stream>>>(mixer_w, mixer_b, tbuf, (float*)d_out, NHW);
}

// Round 9
// 168.358 us; speedup vs baseline: 4.3825x; 1.1809x over previous
//
#include <hip/hip_runtime.h>
#include <hip/hip_bf16.h>
#include <math.h>

// ---------------------------------------------------------------------------
// FASA pipeline for MI355X. B=4, C=128, H=W=128, HEADS=4, dh=32, pool->32x32
// Round 9: dual-query attention (64q/wave) with the PROVEN R6 permlane32_swap
// exchange and unpermuted kv layout (NaN bisect: isolates dual-query delta).
// ---------------------------------------------------------------------------

#define NB   4
#define NC   128
#define NH   128
#define NW   128
#define NHW  16384      // 128*128
#define NKV  1024       // 32*32

typedef float    f32x4  __attribute__((ext_vector_type(4)));
typedef float    f32x16 __attribute__((ext_vector_type(16)));
typedef short    bf16x8 __attribute__((ext_vector_type(8)));
typedef unsigned u32x4v __attribute__((ext_vector_type(4)));

__device__ __forceinline__ unsigned short f2bf(float f) {
  unsigned u = __float_as_uint(f);
  u += 0x7FFF + ((u >> 16) & 1);      // round to nearest even
  return (unsigned short)(u >> 16);
}

// pack two f32 -> bf16x2 in one instr (no builtin on gfx950; T12 recipe)
__device__ __forceinline__ unsigned cvtpk(float lo, float hi) {
  unsigned r;
  asm("v_cvt_pk_bf16_f32 %0, %1, %2" : "=v"(r) : "v"(lo), "v"(hi));
  return r;
}

// ---------------------------------------------------------------------------
// MFMA pointwise 1x1 conv: Y[b][m][n] = bias[m] + sum_c W[m][c] X[b][c][n]
// ---------------------------------------------------------------------------
__global__ __launch_bounds__(256) void pw_gemm_mfma(
    const float* __restrict__ Wmat,   // [Mtot][128]
    const float* __restrict__ bias,   // [Mtot]
    const float* __restrict__ X,      // [B][128][npos] fp32
    float* __restrict__ Y,            // [B][Mtot][npos] fp32
    int npos)
{
  __shared__ short Wlds[128 * 136];

  const int t  = threadIdx.x;
  const int w    = t >> 6;
  const int lane = t & 63;
  const int nl   = lane & 31;
  const int hi   = lane >> 5;
  const int b  = blockIdx.z;
  const int m0 = blockIdx.y * 128;
  const int n0 = blockIdx.x * 128;
  const int Mtot = gridDim.y * 128;

  for (int i = t; i < 128 * 32; i += 256) {
    int row = i >> 5, c4 = (i & 31) * 4;
    float4 wv = *(const float4*)&Wmat[(size_t)(m0 + row) * 128 + c4];
    uint2 pk; pk.x = cvtpk(wv.x, wv.y); pk.y = cvtpk(wv.z, wv.w);
    *(uint2*)&Wlds[row * 136 + c4] = pk;
  }
  __syncthreads();

  const float* Xb = X + (size_t)b * 128 * npos + n0 + w * 32 + nl;

  f32x16 acc[4];
  #pragma unroll
  for (int mg = 0; mg < 4; mg++)
    #pragma unroll
    for (int r = 0; r < 16; r++) acc[mg][r] = 0.f;

  #pragma unroll
  for (int s = 0; s < 8; s++) {
    const float* xp = Xb + (size_t)(s * 16 + hi * 8) * npos;
    float xv[8];
    #pragma unroll
    for (int e = 0; e < 8; e++) xv[e] = xp[(size_t)e * npos];
    u32x4v bu;
    #pragma unroll
    for (int j = 0; j < 4; j++) bu[j] = cvtpk(xv[2 * j], xv[2 * j + 1]);
    bf16x8 bfrag = __builtin_bit_cast(bf16x8, bu);

    #pragma unroll
    for (int mg = 0; mg < 4; mg++) {
      bf16x8 afrag = *(const bf16x8*)&Wlds[(mg * 32 + nl) * 136 + s * 16 + hi * 8];
      acc[mg] = __builtin_amdgcn_mfma_f32_32x32x16_bf16(afrag, bfrag, acc[mg], 0, 0, 0);
    }
  }

  float* Yb = Y + ((size_t)b * Mtot + m0) * npos + n0 + w * 32 + nl;
  #pragma unroll
  for (int mg = 0; mg < 4; mg++)
    #pragma unroll
    for (int r = 0; r < 16; r++) {
      int drow = mg * 32 + (r & 3) + 8 * (r >> 2) + 4 * hi;
      Yb[(size_t)drow * npos] = acc[mg][r] + bias[m0 + drow];
    }
}

// ---------------------------------------------------------------------------
// LDS-tiled stride-2 depthwise 5x5 + BN.
// ---------------------------------------------------------------------------
template<int INH, int INW, int OUTW, int ORPB, int WLSP>
__global__ __launch_bounds__(256) void dw5x5s2_tile(
    const float* __restrict__ in,
    const float* __restrict__ wt, const float* __restrict__ bias,
    const float* __restrict__ g, const float* __restrict__ bt,
    const float* __restrict__ mean, const float* __restrict__ var,
    float* __restrict__ out)
{
  constexpr int IR = 2 * ORPB + 3;
  constexpr int XG = OUTW / 4;
  __shared__ float Ls[IR * WLSP];

  const int t  = threadIdx.x;
  const int c  = blockIdx.y, b = blockIdx.z;
  const int y0 = blockIdx.x * ORPB;
  const float* plane = in + ((size_t)b * NC + c) * INH * INW;

  for (int i = t; i < IR * WLSP / 4; i += 256)
    *(float4*)&Ls[i * 4] = (float4){0.f, 0.f, 0.f, 0.f};
  __syncthreads();

  for (int i = t; i < IR * (INW / 4); i += 256) {
    int r = i / (INW / 4), s4 = (i % (INW / 4)) * 4;
    int gy = 2 * y0 - 2 + r;
    if (gy >= 0 && gy < INH)
      *(float4*)&Ls[r * WLSP + 4 + s4] = *(const float4*)&plane[(size_t)gy * INW + s4];
  }

  float wreg[25];
  #pragma unroll
  for (int i = 0; i < 25; i++) wreg[i] = wt[c * 25 + i];
  const float sc = g[c] * rsqrtf(var[c] + 1e-5f);
  const float off = (bias[c] - mean[c]) * sc + bt[c];
  __syncthreads();

  const int row = t / XG;
  const int x0  = (t % XG) * 4;
  const int r0  = 2 * row;

  float a[4] = {0.f, 0.f, 0.f, 0.f};
  #pragma unroll
  for (int i = 0; i < 5; i++) {
    const float* lr = &Ls[(r0 + i) * WLSP + 2 * x0];
    float4 L0 = *(const float4*)&lr[0];
    float4 L1 = *(const float4*)&lr[4];
    float4 L2 = *(const float4*)&lr[8];
    float4 L3 = *(const float4*)&lr[12];
    float rr[16] = {L0.x,L0.y,L0.z,L0.w, L1.x,L1.y,L1.z,L1.w,
                    L2.x,L2.y,L2.z,L2.w, L3.x,L3.y,L3.z,L3.w};
    #pragma unroll
    for (int j = 0; j < 5; j++) {
      float wv = wreg[i * 5 + j];
      #pragma unroll
      for (int o = 0; o < 4; o++)
        a[o] += wv * rr[2 * o + j + 2];
    }
  }

  float4 ov;
  ov.x = a[0] * sc + off; ov.y = a[1] * sc + off;
  ov.z = a[2] * sc + off; ov.w = a[3] * sc + off;
  const int OH = INH / 2;
  *(float4*)&out[((size_t)b * NC + c) * OH * OUTW + (size_t)(y0 + row) * OUTW + x0] = ov;
}

// ---------------------------------------------------------------------------
// kv prep (R6 layout, unpermuted): kvb fp32 [4][256][1024] ->
//   kT bf16 [16][1024][32], vT bf16 [16][32][1024]
// ---------------------------------------------------------------------------
__global__ __launch_bounds__(256) void kv_prep(
    const float* __restrict__ kvb,
    short* __restrict__ kT, short* __restrict__ vT)
{
  const int t = threadIdx.x;
  const int h = blockIdx.y, b = blockIdx.z;
  const int kpos = blockIdx.x * 256 + t;
  const int bh = b * 4 + h;

  bf16x8 kr[4];
  #pragma unroll
  for (int d = 0; d < 32; d++) {
    float kvv = kvb[((size_t)b * 256 + h * 32 + d) * NKV + kpos];
    float vvv = kvb[((size_t)b * 256 + 128 + h * 32 + d) * NKV + kpos];
    kr[d >> 3][d & 7] = (short)f2bf(kvv);
    vT[(size_t)bh * 32768 + d * NKV + kpos] = (short)f2bf(vvv);
  }
  short* dstk = kT + (size_t)bh * 32768 + (size_t)kpos * 32;
  #pragma unroll
  for (int i = 0; i < 4; i++)
    *(bf16x8*)(dstk + i * 8) = kr[i];
}

// ---------------------------------------------------------------------------
// 32x32 MFMA flash attention, 64 queries per wave (two 32-col sets A/B
// sharing K/V fragments); softmax in-register with the R6-proven
// cvt_pk + v_permlane32_swap exchange.
// ---------------------------------------------------------------------------
__global__ __launch_bounds__(256) void attn_mfma64(
    const float* __restrict__ q_local,   // [4][128][16384] fp32
    const short* __restrict__ kT,        // [16][1024][32] bf16
    const short* __restrict__ vT,        // [16][32][1024] bf16
    float* __restrict__ gf)              // [4][128][16384] fp32
{
  const int t    = threadIdx.x;
  const int w    = t >> 6;
  const int lane = t & 63;
  const int c    = lane & 31;
  const int hi   = lane >> 5;
  const int b    = blockIdx.z, h = blockIdx.y;
  const int q0   = blockIdx.x * 256 + w * 64;
  const int bh   = b * 4 + h;

  const float QSCALE = 0.17677669529663689f * 1.4426950408889634f; // scale*log2e

  // Q^T B-operand frags for columns q0+c (A) and q0+32+c (B)
  bf16x8 qA1, qA2, qB1, qB2;
  {
    const float* qb = q_local + ((size_t)(b * NC + h * 32 + hi * 8)) * NHW + q0 + c;
    float fva[16], fvb[16];
    #pragma unroll
    for (int e = 0; e < 8; e++) {
      fva[e]     = qb[(size_t)e * NHW] * QSCALE;
      fva[8 + e] = qb[(size_t)(16 + e) * NHW] * QSCALE;
      fvb[e]     = qb[(size_t)e * NHW + 32] * QSCALE;
      fvb[8 + e] = qb[(size_t)(16 + e) * NHW + 32] * QSCALE;
    }
    u32x4v u1, u2, u3, u4;
    #pragma unroll
    for (int j = 0; j < 4; j++) {
      u1[j] = cvtpk(fva[2 * j], fva[2 * j + 1]);
      u2[j] = cvtpk(fva[8 + 2 * j], fva[9 + 2 * j]);
      u3[j] = cvtpk(fvb[2 * j], fvb[2 * j + 1]);
      u4[j] = cvtpk(fvb[8 + 2 * j], fvb[9 + 2 * j]);
    }
    qA1 = __builtin_bit_cast(bf16x8, u1); qA2 = __builtin_bit_cast(bf16x8, u2);
    qB1 = __builtin_bit_cast(bf16x8, u3); qB2 = __builtin_bit_cast(bf16x8, u4);
  }

  const short* kbh = kT + (size_t)bh * 32768;
  const short* vbh = vT + (size_t)bh * 32768;

  f32x16 oA, oB;
  #pragma unroll
  for (int r = 0; r < 16; r++) { oA[r] = 0.f; oB[r] = 0.f; }
  const f32x16 zf = oA;
  float lsumA = 0.f, lsumB = 0.f;

  bf16x8 ka  = *(const bf16x8*)(kbh + (size_t)c * 32 + hi * 8);
  bf16x8 kb2 = *(const bf16x8*)(kbh + (size_t)c * 32 + 16 + hi * 8);
  bf16x8 va  = *(const bf16x8*)(vbh + (size_t)c * NKV + hi * 8);
  bf16x8 vb2 = *(const bf16x8*)(vbh + (size_t)c * NKV + 16 + hi * 8);

  for (int kt = 0; kt < 32; kt++) {
    const int k0n = (kt < 31) ? (kt + 1) * 32 : 0;
    bf16x8 nka  = *(const bf16x8*)(kbh + (size_t)(k0n + c) * 32 + hi * 8);
    bf16x8 nkb  = *(const bf16x8*)(kbh + (size_t)(k0n + c) * 32 + 16 + hi * 8);
    bf16x8 nva  = *(const bf16x8*)(vbh + (size_t)c * NKV + k0n + hi * 8);
    bf16x8 nvb  = *(const bf16x8*)(vbh + (size_t)c * NKV + k0n + 16 + hi * 8);

    // ---- column set A ----
    {
      f32x16 s = __builtin_amdgcn_mfma_f32_32x32x16_bf16(ka,  qA1, zf, 0, 0, 0);
      s        = __builtin_amdgcn_mfma_f32_32x32x16_bf16(kb2, qA2, s,  0, 0, 0);
      float p[16];
      #pragma unroll
      for (int r = 0; r < 16; r++) p[r] = __builtin_amdgcn_exp2f(s[r]);
      float s0 = (p[0] + p[1]) + (p[2] + p[3]);
      float s1 = (p[4] + p[5]) + (p[6] + p[7]);
      float s2 = (p[8] + p[9]) + (p[10] + p[11]);
      float s3 = (p[12] + p[13]) + (p[14] + p[15]);
      lsumA += (s0 + s1) + (s2 + s3);

      unsigned a0 = cvtpk(p[0],  p[1]);
      unsigned a1 = cvtpk(p[2],  p[3]);
      unsigned a2 = cvtpk(p[4],  p[5]);
      unsigned a3 = cvtpk(p[6],  p[7]);
      unsigned a4 = cvtpk(p[8],  p[9]);
      unsigned a5 = cvtpk(p[10], p[11]);
      unsigned a6 = cvtpk(p[12], p[13]);
      unsigned a7 = cvtpk(p[14], p[15]);
      asm("v_permlane32_swap_b32 %0, %1" : "+v"(a0), "+v"(a2));
      asm("v_permlane32_swap_b32 %0, %1" : "+v"(a1), "+v"(a3));
      asm("v_permlane32_swap_b32 %0, %1" : "+v"(a4), "+v"(a6));
      asm("v_permlane32_swap_b32 %0, %1" : "+v"(a5), "+v"(a7));
      u32x4v b1u = {a0, a1, a2, a3};
      u32x4v b2u = {a4, a5, a6, a7};
      bf16x8 pb1 = __builtin_bit_cast(bf16x8, b1u);
      bf16x8 pb2 = __builtin_bit_cast(bf16x8, b2u);
      oA = __builtin_amdgcn_mfma_f32_32x32x16_bf16(va,  pb1, oA, 0, 0, 0);
      oA = __builtin_amdgcn_mfma_f32_32x32x16_bf16(vb2, pb2, oA, 0, 0, 0);
    }

    // ---- column set B ----
    {
      f32x16 s = __builtin_amdgcn_mfma_f32_32x32x16_bf16(ka,  qB1, zf, 0, 0, 0);
      s        = __builtin_amdgcn_mfma_f32_32x32x16_bf16(kb2, qB2, s,  0, 0, 0);
      float p[16];
      #pragma unroll
      for (int r = 0; r < 16; r++) p[r] = __builtin_amdgcn_exp2f(s[r]);
      float s0 = (p[0] + p[1]) + (p[2] + p[3]);
      float s1 = (p[4] + p[5]) + (p[6] + p[7]);
      float s2 = (p[8] + p[9]) + (p[10] + p[11]);
      float s3 = (p[12] + p[13]) + (p[14] + p[15]);
      lsumB += (s0 + s1) + (s2 + s3);

      unsigned a0 = cvtpk(p[0],  p[1]);
      unsigned a1 = cvtpk(p[2],  p[3]);
      unsigned a2 = cvtpk(p[4],  p[5]);
      unsigned a3 = cvtpk(p[6],  p[7]);
      unsigned a4 = cvtpk(p[8],  p[9]);
      unsigned a5 = cvtpk(p[10], p[11]);
      unsigned a6 = cvtpk(p[12], p[13]);
      unsigned a7 = cvtpk(p[14], p[15]);
      asm("v_permlane32_swap_b32 %0, %1" : "+v"(a0), "+v"(a2));
      asm("v_permlane32_swap_b32 %0, %1" : "+v"(a1), "+v"(a3));
      asm("v_permlane32_swap_b32 %0, %1" : "+v"(a4), "+v"(a6));
      asm("v_permlane32_swap_b32 %0, %1" : "+v"(a5), "+v"(a7));
      u32x4v b1u = {a0, a1, a2, a3};
      u32x4v b2u = {a4, a5, a6, a7};
      bf16x8 pb1 = __builtin_bit_cast(bf16x8, b1u);
      bf16x8 pb2 = __builtin_bit_cast(bf16x8, b2u);
      oB = __builtin_amdgcn_mfma_f32_32x32x16_bf16(va,  pb1, oB, 0, 0, 0);
      oB = __builtin_amdgcn_mfma_f32_32x32x16_bf16(vb2, pb2, oB, 0, 0, 0);
    }

    ka = nka; kb2 = nkb; va = nva; vb2 = nvb;
  }

  lsumA += __shfl_xor(lsumA, 32);
  lsumB += __shfl_xor(lsumB, 32);
  float invA = 1.f / lsumA;
  float invB = 1.f / lsumB;

  float* gfb = gf + ((size_t)(b * NC + h * 32)) * NHW + q0 + c;
  #pragma unroll
  for (int r = 0; r < 16; r++) {
    int d = (r & 3) + 8 * (r >> 2) + 4 * hi;
    gfb[(size_t)d * NHW]      = oA[r] * invA;
    gfb[(size_t)d * NHW + 32] = oB[r] * invB;
  }
}

// ---------------------------------------------------------------------------
// LDS-tiled lf_fuse: lf = dw5x5_s1(q_local)+local_b; t = lf*sig(lf)*sig(gf)*gf
// ---------------------------------------------------------------------------
__global__ __launch_bounds__(256) void lf_fuse_tile(
    const float* __restrict__ qloc, const float* __restrict__ gf,
    const float* __restrict__ wt, const float* __restrict__ bias,
    float* __restrict__ tout)
{
  __shared__ float Ls[12 * 140];

  const int t  = threadIdx.x;
  const int c  = blockIdx.y, b = blockIdx.z;
  const int y0 = blockIdx.x * 8;
  const float* plane = qloc + ((size_t)b * NC + c) * NHW;

  for (int i = t; i < 12 * 140 / 4; i += 256)
    *(float4*)&Ls[i * 4] = (float4){0.f, 0.f, 0.f, 0.f};
  __syncthreads();

  for (int i = t; i < 12 * 32; i += 256) {
    int r = i >> 5, s4 = (i & 31) * 4;
    int gy = y0 - 2 + r;
    if (gy >= 0 && gy < NH)
      *(float4*)&Ls[r * 140 + 4 + s4] = *(const float4*)&plane[(size_t)gy * NW + s4];
  }

  float wreg[25];
  #pragma unroll
  for (int i = 0; i < 25; i++) wreg[i] = wt[c * 25 + i];
  const float bs = bias[c];
  __syncthreads();

  const int row = t >> 5;
  const int x0  = (t & 31) * 4;

  float a[4] = {bs, bs, bs, bs};
  #pragma unroll
  for (int i = 0; i < 5; i++) {
    const float* lr = &Ls[(row + i) * 140 + x0];
    float4 L0 = *(const float4*)&lr[0];
    float4 L1 = *(const float4*)&lr[4];
    float4 L2 = *(const float4*)&lr[8];
    float rr[12] = {L0.x,L0.y,L0.z,L0.w, L1.x,L1.y,L1.z,L1.w,
                    L2.x,L2.y,L2.z,L2.w};
    #pragma unroll
    for (int j = 0; j < 5; j++) {
      float wv = wreg[i * 5 + j];
      #pragma unroll
      for (int o = 0; o < 4; o++)
        a[o] += wv * rr[o + j + 2];
    }
  }

  size_t base = ((size_t)b * NC + c) * NHW + (size_t)(y0 + row) * NW + x0;
  float4 gv4 = *(const float4*)&gf[base];
  float gvv[4] = {gv4.x, gv4.y, gv4.z, gv4.w};
  float4 ov;
  float* op = (float*)&ov;
  #pragma unroll
  for (int k = 0; k < 4; k++) {
    float sl = a[k] / (1.f + __expf(-a[k]));
    float sg = 1.f / (1.f + __expf(-gvv[k]));
    op[k] = sl * sg * gvv[k];
  }
  *(float4*)&tout[base] = ov;
}

// ---------------------------------------------------------------------------
extern "C" void kernel_launch(void* const* d_in, const int* in_sizes, int n_in,
                              void* d_out, int out_size, void* d_ws, size_t ws_size,
                              hipStream_t stream) {
  const float* x       = (const float*)d_in[0];
  const float* q_w     = (const float*)d_in[1];
  const float* q_b     = (const float*)d_in[2];
  const float* kv_w    = (const float*)d_in[3];
  const float* kv_b    = (const float*)d_in[4];
  const float* local_w = (const float*)d_in[5];
  const float* local_b = (const float*)d_in[6];
  const float* mixer_w = (const float*)d_in[7];
  const float* mixer_b = (const float*)d_in[8];
  const float* p0_w    = (const float*)d_in[9];
  const float* p0_b    = (const float*)d_in[10];
  const float* bn0_g   = (const float*)d_in[11];
  const float* bn0_b   = (const float*)d_in[12];
  const float* bn0_m   = (const float*)d_in[13];
  const float* bn0_v   = (const float*)d_in[14];
  const float* lin0_w  = (const float*)d_in[15];
  const float* lin0_b  = (const float*)d_in[16];
  const float* p1_w    = (const float*)d_in[17];
  const float* p1_b    = (const float*)d_in[18];
  const float* bn1_g   = (const float*)d_in[19];
  const float* bn1_b   = (const float*)d_in[20];
  const float* bn1_m   = (const float*)d_in[21];
  const float* bn1_v   = (const float*)d_in[22];

  float* ws = (float*)d_ws;
  float* q_local = ws;                     // 8,388,608 floats
  float* gf      = ws + 8388608;           // 8,388,608
  float* tbuf    = ws + 16777216;          // 8,388,608
  float* p0      = ws + 25165824;          // 2,097,152
  float* lin0b   = ws + 27262976;          // 2,097,152
  float* p1      = ws + 29360128;          // 524,288
  float* kvb     = ws + 29884416;          // 1,048,576  (4x256x1024)
  short* kT      = (short*)(ws + 30932992);    // 524,288 shorts = 1 MB
  short* vT      = kT + 524288;                // 524,288 shorts

  // 1) q_local = pw(x, q_w) + q_b
  pw_gemm_mfma<<<dim3(NHW / 128, 1, NB), 256, 0, stream>>>(q_w, q_b, x, q_local, NHW);
  // 2) p0 = bn0(dw5x5_s2(x) + p0_b)          -> 64x64
  dw5x5s2_tile<128, 128, 64, 16, 140><<<dim3(4, NC, NB), 256, 0, stream>>>(
      x, p0_w, p0_b, bn0_g, bn0_b, bn0_m, bn0_v, p0);
  // 3) lin0 = pw(p0, lin0_w) + lin0_b
  pw_gemm_mfma<<<dim3(4096 / 128, 1, NB), 256, 0, stream>>>(lin0_w, lin0_b, p0, lin0b, 4096);
  // 4) p1 = bn1(dw5x5_s2(lin0) + p1_b)       -> 32x32
  dw5x5s2_tile<64, 64, 32, 32, 76><<<dim3(1, NC, NB), 256, 0, stream>>>(
      lin0b, p1_w, p1_b, bn1_g, bn1_b, bn1_m, bn1_v, p1);
  // 5) kv = pw(p1, kv_w) + kv_b   (256 out channels)
  pw_gemm_mfma<<<dim3(NKV / 128, 2, NB), 256, 0, stream>>>(kv_w, kv_b, p1, kvb, NKV);
  // 6) kv -> bf16 kT [bh][kpos][32], vT [bh][d][kpos]
  kv_prep<<<dim3(4, 4, NB), 256, 0, stream>>>(kvb, kT, vT);
  // 7) MFMA attention -> gf   (64 q per wave, 4 waves/block)
  attn_mfma64<<<dim3(NHW / 256, 4, NB), 256, 0, stream>>>(q_local, kT, vT, gf);
  // 8) lf dwconv + elementwise fuse -> tbuf
  lf_fuse_tile<<<dim3(16, NC, NB), 256, 0, stream>>>(q_local, gf, local_w, local_b, tbuf);
  // 9) out = pw(tbuf, mixer_w) + mixer_b
  pw_gemm_mfma<<<dim3(NHW / 128, 1, NB), 256, 0, stream>>>(mixer_w, mixer_b, tbuf, (float*)d_out, NHW);
}

// Round 10
// 153.351 us; speedup vs baseline: 4.8114x; 1.0979x over previous
//
#include <hip/hip_runtime.h>
#include <hip/hip_bf16.h>
#include <math.h>

// ---------------------------------------------------------------------------
// FASA pipeline for MI355X. B=4, C=128, H=W=128, HEADS=4, dh=32, pool->32x32
// Round 10: split-K attention (8-wave blocks, LDS combine); bf16 q_local/tbuf.
// ---------------------------------------------------------------------------

#define NB   4
#define NC   128
#define NH   128
#define NW   128
#define NHW  16384      // 128*128
#define NKV  1024       // 32*32

typedef float    f32x4  __attribute__((ext_vector_type(4)));
typedef float    f32x16 __attribute__((ext_vector_type(16)));
typedef short    bf16x8 __attribute__((ext_vector_type(8)));
typedef unsigned u32x4v __attribute__((ext_vector_type(4)));

__device__ __forceinline__ unsigned short f2bf(float f) {
  unsigned u = __float_as_uint(f);
  u += 0x7FFF + ((u >> 16) & 1);      // round to nearest even
  return (unsigned short)(u >> 16);
}

__device__ __forceinline__ float bf2f(unsigned short u) {
  return __uint_as_float((unsigned)u << 16);
}

// pack two f32 -> bf16x2 in one instr (no builtin on gfx950; T12 recipe)
__device__ __forceinline__ unsigned cvtpk(float lo, float hi) {
  unsigned r;
  asm("v_cvt_pk_bf16_f32 %0, %1, %2" : "=v"(r) : "v"(lo), "v"(hi));
  return r;
}

// ---------------------------------------------------------------------------
// MFMA pointwise 1x1 conv: Y[b][m][n] = bias[m] + sum_c W[m][c] X[b][c][n]
// IN_BF16: X is bf16; OUT_BF16: Y written as bf16.
// ---------------------------------------------------------------------------
template<bool IN_BF16, bool OUT_BF16>
__global__ __launch_bounds__(256) void pw_gemm_mfma(
    const float* __restrict__ Wmat,   // [Mtot][128]
    const float* __restrict__ bias,   // [Mtot]
    const void* __restrict__ Xv,      // [B][128][npos]
    void* __restrict__ Yv,            // [B][Mtot][npos]
    int npos, int Mtot)
{
  __shared__ short Wlds[128 * 136];

  const int t  = threadIdx.x;
  const int w    = t >> 6;
  const int lane = t & 63;
  const int nl   = lane & 31;
  const int hi   = lane >> 5;
  const int b  = blockIdx.z;
  const int m0 = blockIdx.y * 128;
  const int n0 = blockIdx.x * 128;

  for (int i = t; i < 128 * 32; i += 256) {
    int row = i >> 5, c4 = (i & 31) * 4;
    float4 wv = *(const float4*)&Wmat[(size_t)(m0 + row) * 128 + c4];
    uint2 pk; pk.x = cvtpk(wv.x, wv.y); pk.y = cvtpk(wv.z, wv.w);
    *(uint2*)&Wlds[row * 136 + c4] = pk;
  }
  __syncthreads();

  f32x16 acc[4];
  #pragma unroll
  for (int mg = 0; mg < 4; mg++)
    #pragma unroll
    for (int r = 0; r < 16; r++) acc[mg][r] = 0.f;

  #pragma unroll
  for (int s = 0; s < 8; s++) {
    bf16x8 bfrag;
    if constexpr (IN_BF16) {
      const unsigned short* Xb = (const unsigned short*)Xv
          + (size_t)b * 128 * npos + n0 + w * 32 + nl;
      const unsigned short* xp = Xb + (size_t)(s * 16 + hi * 8) * npos;
      #pragma unroll
      for (int e = 0; e < 8; e++) bfrag[e] = (short)xp[(size_t)e * npos];
    } else {
      const float* Xb = (const float*)Xv + (size_t)b * 128 * npos + n0 + w * 32 + nl;
      const float* xp = Xb + (size_t)(s * 16 + hi * 8) * npos;
      float xv[8];
      #pragma unroll
      for (int e = 0; e < 8; e++) xv[e] = xp[(size_t)e * npos];
      u32x4v bu;
      #pragma unroll
      for (int j = 0; j < 4; j++) bu[j] = cvtpk(xv[2 * j], xv[2 * j + 1]);
      bfrag = __builtin_bit_cast(bf16x8, bu);
    }

    #pragma unroll
    for (int mg = 0; mg < 4; mg++) {
      bf16x8 afrag = *(const bf16x8*)&Wlds[(mg * 32 + nl) * 136 + s * 16 + hi * 8];
      acc[mg] = __builtin_amdgcn_mfma_f32_32x32x16_bf16(afrag, bfrag, acc[mg], 0, 0, 0);
    }
  }

  #pragma unroll
  for (int mg = 0; mg < 4; mg++)
    #pragma unroll
    for (int r = 0; r < 16; r++) {
      int drow = mg * 32 + (r & 3) + 8 * (r >> 2) + 4 * hi;
      float val = acc[mg][r] + bias[m0 + drow];
      if constexpr (OUT_BF16) {
        unsigned short* Yb = (unsigned short*)Yv
            + ((size_t)b * Mtot + m0) * npos + n0 + w * 32 + nl;
        Yb[(size_t)drow * npos] = f2bf(val);
      } else {
        float* Yb = (float*)Yv + ((size_t)b * Mtot + m0) * npos + n0 + w * 32 + nl;
        Yb[(size_t)drow * npos] = val;
      }
    }
}

// ---------------------------------------------------------------------------
// LDS-tiled stride-2 depthwise 5x5 + BN.
// ---------------------------------------------------------------------------
template<int INH, int INW, int OUTW, int ORPB, int WLSP>
__global__ __launch_bounds__(256) void dw5x5s2_tile(
    const float* __restrict__ in,
    const float* __restrict__ wt, const float* __restrict__ bias,
    const float* __restrict__ g, const float* __restrict__ bt,
    const float* __restrict__ mean, const float* __restrict__ var,
    float* __restrict__ out)
{
  constexpr int IR = 2 * ORPB + 3;
  constexpr int XG = OUTW / 4;
  __shared__ float Ls[IR * WLSP];

  const int t  = threadIdx.x;
  const int c  = blockIdx.y, b = blockIdx.z;
  const int y0 = blockIdx.x * ORPB;
  const float* plane = in + ((size_t)b * NC + c) * INH * INW;

  for (int i = t; i < IR * WLSP / 4; i += 256)
    *(float4*)&Ls[i * 4] = (float4){0.f, 0.f, 0.f, 0.f};
  __syncthreads();

  for (int i = t; i < IR * (INW / 4); i += 256) {
    int r = i / (INW / 4), s4 = (i % (INW / 4)) * 4;
    int gy = 2 * y0 - 2 + r;
    if (gy >= 0 && gy < INH)
      *(float4*)&Ls[r * WLSP + 4 + s4] = *(const float4*)&plane[(size_t)gy * INW + s4];
  }

  float wreg[25];
  #pragma unroll
  for (int i = 0; i < 25; i++) wreg[i] = wt[c * 25 + i];
  const float sc = g[c] * rsqrtf(var[c] + 1e-5f);
  const float off = (bias[c] - mean[c]) * sc + bt[c];
  __syncthreads();

  const int row = t / XG;
  const int x0  = (t % XG) * 4;
  const int r0  = 2 * row;

  float a[4] = {0.f, 0.f, 0.f, 0.f};
  #pragma unroll
  for (int i = 0; i < 5; i++) {
    const float* lr = &Ls[(r0 + i) * WLSP + 2 * x0];
    float4 L0 = *(const float4*)&lr[0];
    float4 L1 = *(const float4*)&lr[4];
    float4 L2 = *(const float4*)&lr[8];
    float4 L3 = *(const float4*)&lr[12];
    float rr[16] = {L0.x,L0.y,L0.z,L0.w, L1.x,L1.y,L1.z,L1.w,
                    L2.x,L2.y,L2.z,L2.w, L3.x,L3.y,L3.z,L3.w};
    #pragma unroll
    for (int j = 0; j < 5; j++) {
      float wv = wreg[i * 5 + j];
      #pragma unroll
      for (int o = 0; o < 4; o++)
        a[o] += wv * rr[2 * o + j + 2];
    }
  }

  float4 ov;
  ov.x = a[0] * sc + off; ov.y = a[1] * sc + off;
  ov.z = a[2] * sc + off; ov.w = a[3] * sc + off;
  const int OH = INH / 2;
  *(float4*)&out[((size_t)b * NC + c) * OH * OUTW + (size_t)(y0 + row) * OUTW + x0] = ov;
}

// ---------------------------------------------------------------------------
// kv prep: kvb fp32 [4][256][1024] -> kT bf16 [16][1024][32], vT bf16 [16][32][1024]
// ---------------------------------------------------------------------------
__global__ __launch_bounds__(256) void kv_prep(
    const float* __restrict__ kvb,
    short* __restrict__ kT, short* __restrict__ vT)
{
  const int t = threadIdx.x;
  const int h = blockIdx.y, b = blockIdx.z;
  const int kpos = blockIdx.x * 256 + t;
  const int bh = b * 4 + h;

  bf16x8 kr[4];
  #pragma unroll
  for (int d = 0; d < 32; d++) {
    float kvv = kvb[((size_t)b * 256 + h * 32 + d) * NKV + kpos];
    float vvv = kvb[((size_t)b * 256 + 128 + h * 32 + d) * NKV + kpos];
    kr[d >> 3][d & 7] = (short)f2bf(kvv);
    vT[(size_t)bh * 32768 + d * NKV + kpos] = (short)f2bf(vvv);
  }
  short* dstk = kT + (size_t)bh * 32768 + (size_t)kpos * 32;
  #pragma unroll
  for (int i = 0; i < 4; i++)
    *(bf16x8*)(dstk + i * 8) = kr[i];
}

// ---------------------------------------------------------------------------
// Split-K dual-query 32x32 MFMA flash attention.
// 512 thr = 8 waves: wave w -> query group (w&3, 64 q), key half (w>>2).
// Per-half loop body is the R9-proven code; halves combined through LDS.
// ---------------------------------------------------------------------------
__global__ __launch_bounds__(512) void attn_mfma64(
    const unsigned short* __restrict__ q16,  // [4][128][16384] bf16
    const short* __restrict__ kT,            // [16][1024][32] bf16
    const short* __restrict__ vT,            // [16][32][1024] bf16
    float* __restrict__ gf)                  // [4][128][16384] fp32
{
  __shared__ float Cmb[4][64][34];

  const int t    = threadIdx.x;
  const int w    = t >> 6;          // 0..7
  const int lane = t & 63;
  const int c    = lane & 31;
  const int hi   = lane >> 5;
  const int qg   = w & 3;
  const int half = w >> 2;
  const int b    = blockIdx.z, h = blockIdx.y;
  const int q0   = blockIdx.x * 256 + qg * 64;
  const int bh   = b * 4 + h;
  const int base = half * 16;       // first 32-key tile of this half

  const float QSCALE = 0.17677669529663689f * 1.4426950408889634f; // scale*log2e

  // Q^T B-operand frags for columns q0+c (A) and q0+32+c (B), from bf16
  bf16x8 qA1, qA2, qB1, qB2;
  {
    const unsigned short* qb = q16 + ((size_t)(b * NC + h * 32 + hi * 8)) * NHW + q0 + c;
    float fva[16], fvb[16];
    #pragma unroll
    for (int e = 0; e < 8; e++) {
      fva[e]     = bf2f(qb[(size_t)e * NHW]) * QSCALE;
      fva[8 + e] = bf2f(qb[(size_t)(16 + e) * NHW]) * QSCALE;
      fvb[e]     = bf2f(qb[(size_t)e * NHW + 32]) * QSCALE;
      fvb[8 + e] = bf2f(qb[(size_t)(16 + e) * NHW + 32]) * QSCALE;
    }
    u32x4v u1, u2, u3, u4;
    #pragma unroll
    for (int j = 0; j < 4; j++) {
      u1[j] = cvtpk(fva[2 * j], fva[2 * j + 1]);
      u2[j] = cvtpk(fva[8 + 2 * j], fva[9 + 2 * j]);
      u3[j] = cvtpk(fvb[2 * j], fvb[2 * j + 1]);
      u4[j] = cvtpk(fvb[8 + 2 * j], fvb[9 + 2 * j]);
    }
    qA1 = __builtin_bit_cast(bf16x8, u1); qA2 = __builtin_bit_cast(bf16x8, u2);
    qB1 = __builtin_bit_cast(bf16x8, u3); qB2 = __builtin_bit_cast(bf16x8, u4);
  }

  const short* kbh = kT + (size_t)bh * 32768;
  const short* vbh = vT + (size_t)bh * 32768;

  f32x16 oA, oB;
  #pragma unroll
  for (int r = 0; r < 16; r++) { oA[r] = 0.f; oB[r] = 0.f; }
  const f32x16 zf = oA;
  float lsumA = 0.f, lsumB = 0.f;

  const int kbase = base * 32;
  bf16x8 ka  = *(const bf16x8*)(kbh + (size_t)(kbase + c) * 32 + hi * 8);
  bf16x8 kb2 = *(const bf16x8*)(kbh + (size_t)(kbase + c) * 32 + 16 + hi * 8);
  bf16x8 va  = *(const bf16x8*)(vbh + (size_t)c * NKV + kbase + hi * 8);
  bf16x8 vb2 = *(const bf16x8*)(vbh + (size_t)c * NKV + kbase + 16 + hi * 8);

  for (int kt = 0; kt < 16; kt++) {
    const int k0n = (kt < 15) ? (kbase + (kt + 1) * 32) : 0;
    bf16x8 nka  = *(const bf16x8*)(kbh + (size_t)(k0n + c) * 32 + hi * 8);
    bf16x8 nkb  = *(const bf16x8*)(kbh + (size_t)(k0n + c) * 32 + 16 + hi * 8);
    bf16x8 nva  = *(const bf16x8*)(vbh + (size_t)c * NKV + k0n + hi * 8);
    bf16x8 nvb  = *(const bf16x8*)(vbh + (size_t)c * NKV + k0n + 16 + hi * 8);

    // ---- column set A ----
    {
      f32x16 s = __builtin_amdgcn_mfma_f32_32x32x16_bf16(ka,  qA1, zf, 0, 0, 0);
      s        = __builtin_amdgcn_mfma_f32_32x32x16_bf16(kb2, qA2, s,  0, 0, 0);
      float p[16];
      #pragma unroll
      for (int r = 0; r < 16; r++) p[r] = __builtin_amdgcn_exp2f(s[r]);
      float s0 = (p[0] + p[1]) + (p[2] + p[3]);
      float s1 = (p[4] + p[5]) + (p[6] + p[7]);
      float s2 = (p[8] + p[9]) + (p[10] + p[11]);
      float s3 = (p[12] + p[13]) + (p[14] + p[15]);
      lsumA += (s0 + s1) + (s2 + s3);

      unsigned a0 = cvtpk(p[0],  p[1]);
      unsigned a1 = cvtpk(p[2],  p[3]);
      unsigned a2 = cvtpk(p[4],  p[5]);
      unsigned a3 = cvtpk(p[6],  p[7]);
      unsigned a4 = cvtpk(p[8],  p[9]);
      unsigned a5 = cvtpk(p[10], p[11]);
      unsigned a6 = cvtpk(p[12], p[13]);
      unsigned a7 = cvtpk(p[14], p[15]);
      asm("v_permlane32_swap_b32 %0, %1" : "+v"(a0), "+v"(a2));
      asm("v_permlane32_swap_b32 %0, %1" : "+v"(a1), "+v"(a3));
      asm("v_permlane32_swap_b32 %0, %1" : "+v"(a4), "+v"(a6));
      asm("v_permlane32_swap_b32 %0, %1" : "+v"(a5), "+v"(a7));
      u32x4v b1u = {a0, a1, a2, a3};
      u32x4v b2u = {a4, a5, a6, a7};
      bf16x8 pb1 = __builtin_bit_cast(bf16x8, b1u);
      bf16x8 pb2 = __builtin_bit_cast(bf16x8, b2u);
      oA = __builtin_amdgcn_mfma_f32_32x32x16_bf16(va,  pb1, oA, 0, 0, 0);
      oA = __builtin_amdgcn_mfma_f32_32x32x16_bf16(vb2, pb2, oA, 0, 0, 0);
    }

    // ---- column set B ----
    {
      f32x16 s = __builtin_amdgcn_mfma_f32_32x32x16_bf16(ka,  qB1, zf, 0, 0, 0);
      s        = __builtin_amdgcn_mfma_f32_32x32x16_bf16(kb2, qB2, s,  0, 0, 0);
      float p[16];
      #pragma unroll
      for (int r = 0; r < 16; r++) p[r] = __builtin_amdgcn_exp2f(s[r]);
      float s0 = (p[0] + p[1]) + (p[2] + p[3]);
      float s1 = (p[4] + p[5]) + (p[6] + p[7]);
      float s2 = (p[8] + p[9]) + (p[10] + p[11]);
      float s3 = (p[12] + p[13]) + (p[14] + p[15]);
      lsumB += (s0 + s1) + (s2 + s3);

      unsigned a0 = cvtpk(p[0],  p[1]);
      unsigned a1 = cvtpk(p[2],  p[3]);
      unsigned a2 = cvtpk(p[4],  p[5]);
      unsigned a3 = cvtpk(p[6],  p[7]);
      unsigned a4 = cvtpk(p[8],  p[9]);
      unsigned a5 = cvtpk(p[10], p[11]);
      unsigned a6 = cvtpk(p[12], p[13]);
      unsigned a7 = cvtpk(p[14], p[15]);
      asm("v_permlane32_swap_b32 %0, %1" : "+v"(a0), "+v"(a2));
      asm("v_permlane32_swap_b32 %0, %1" : "+v"(a1), "+v"(a3));
      asm("v_permlane32_swap_b32 %0, %1" : "+v"(a4), "+v"(a6));
      asm("v_permlane32_swap_b32 %0, %1" : "+v"(a5), "+v"(a7));
      u32x4v b1u = {a0, a1, a2, a3};
      u32x4v b2u = {a4, a5, a6, a7};
      bf16x8 pb1 = __builtin_bit_cast(bf16x8, b1u);
      bf16x8 pb2 = __builtin_bit_cast(bf16x8, b2u);
      oB = __builtin_amdgcn_mfma_f32_32x32x16_bf16(va,  pb1, oB, 0, 0, 0);
      oB = __builtin_amdgcn_mfma_f32_32x32x16_bf16(vb2, pb2, oB, 0, 0, 0);
    }

    ka = nka; kb2 = nkb; va = nva; vb2 = nvb;
  }

  // combine halves through LDS: half1 deposits, half0 reduces + stores
  if (half) {
    float* dst = &Cmb[qg][lane][0];
    #pragma unroll
    for (int r = 0; r < 16; r++) { dst[r] = oA[r]; dst[16 + r] = oB[r]; }
    dst[32] = lsumA; dst[33] = lsumB;
  }
  __syncthreads();
  if (!half) {
    const float* src = &Cmb[qg][lane][0];
    #pragma unroll
    for (int r = 0; r < 16; r++) { oA[r] += src[r]; oB[r] += src[16 + r]; }
    lsumA += src[32]; lsumB += src[33];

    lsumA += __shfl_xor(lsumA, 32);
    lsumB += __shfl_xor(lsumB, 32);
    float invA = 1.f / lsumA;
    float invB = 1.f / lsumB;

    float* gfb = gf + ((size_t)(b * NC + h * 32)) * NHW + q0 + c;
    #pragma unroll
    for (int r = 0; r < 16; r++) {
      int d = (r & 3) + 8 * (r >> 2) + 4 * hi;
      gfb[(size_t)d * NHW]      = oA[r] * invA;
      gfb[(size_t)d * NHW + 32] = oB[r] * invB;
    }
  }
}

// ---------------------------------------------------------------------------
// LDS-tiled lf_fuse: lf = dw5x5_s1(q16)+local_b; t16 = bf16(lf*sig(lf)*sig(gf)*gf)
// q16 bf16 input expanded to f32 during LDS staging; gf fp32.
// ---------------------------------------------------------------------------
__global__ __launch_bounds__(256) void lf_fuse_tile(
    const unsigned short* __restrict__ q16, const float* __restrict__ gf,
    const float* __restrict__ wt, const float* __restrict__ bias,
    unsigned short* __restrict__ t16)
{
  __shared__ float Ls[12 * 140];

  const int t  = threadIdx.x;
  const int c  = blockIdx.y, b = blockIdx.z;
  const int y0 = blockIdx.x * 8;
  const unsigned short* plane = q16 + ((size_t)b * NC + c) * NHW;

  for (int i = t; i < 12 * 140 / 4; i += 256)
    *(float4*)&Ls[i * 4] = (float4){0.f, 0.f, 0.f, 0.f};
  __syncthreads();

  // stage bf16 -> f32: 12 rows x 128 cols, 8 elems per iteration
  for (int i = t; i < 12 * 16; i += 256) {
    int r = i >> 4, s8 = (i & 15) * 8;
    int gy = y0 - 2 + r;
    if (gy >= 0 && gy < NH) {
      bf16x8 v = *(const bf16x8*)&plane[(size_t)gy * NW + s8];
      float* dp = &Ls[r * 140 + 4 + s8];
      #pragma unroll
      for (int j = 0; j < 8; j++) dp[j] = bf2f((unsigned short)v[j]);
    }
  }

  float wreg[25];
  #pragma unroll
  for (int i = 0; i < 25; i++) wreg[i] = wt[c * 25 + i];
  const float bs = bias[c];
  __syncthreads();

  const int row = t >> 5;
  const int x0  = (t & 31) * 4;

  float a[4] = {bs, bs, bs, bs};
  #pragma unroll
  for (int i = 0; i < 5; i++) {
    const float* lr = &Ls[(row + i) * 140 + x0];
    float4 L0 = *(const float4*)&lr[0];
    float4 L1 = *(const float4*)&lr[4];
    float4 L2 = *(const float4*)&lr[8];
    float rr[12] = {L0.x,L0.y,L0.z,L0.w, L1.x,L1.y,L1.z,L1.w,
                    L2.x,L2.y,L2.z,L2.w};
    #pragma unroll
    for (int j = 0; j < 5; j++) {
      float wv = wreg[i * 5 + j];
      #pragma unroll
      for (int o = 0; o < 4; o++)
        a[o] += wv * rr[o + j + 2];
    }
  }

  size_t base = ((size_t)b * NC + c) * NHW + (size_t)(y0 + row) * NW + x0;
  float4 gv4 = *(const float4*)&gf[base];
  float gvv[4] = {gv4.x, gv4.y, gv4.z, gv4.w};
  float op[4];
  #pragma unroll
  for (int k = 0; k < 4; k++) {
    float sl = a[k] / (1.f + __expf(-a[k]));
    float sg = 1.f / (1.f + __expf(-gvv[k]));
    op[k] = sl * sg * gvv[k];
  }
  uint2 ov;
  ov.x = cvtpk(op[0], op[1]);
  ov.y = cvtpk(op[2], op[3]);
  *(uint2*)&t16[base] = ov;
}

// ---------------------------------------------------------------------------
extern "C" void kernel_launch(void* const* d_in, const int* in_sizes, int n_in,
                              void* d_out, int out_size, void* d_ws, size_t ws_size,
                              hipStream_t stream) {
  const float* x       = (const float*)d_in[0];
  const float* q_w     = (const float*)d_in[1];
  const float* q_b     = (const float*)d_in[2];
  const float* kv_w    = (const float*)d_in[3];
  const float* kv_b    = (const float*)d_in[4];
  const float* local_w = (const float*)d_in[5];
  const float* local_b = (const float*)d_in[6];
  const float* mixer_w = (const float*)d_in[7];
  const float* mixer_b = (const float*)d_in[8];
  const float* p0_w    = (const float*)d_in[9];
  const float* p0_b    = (const float*)d_in[10];
  const float* bn0_g   = (const float*)d_in[11];
  const float* bn0_b   = (const float*)d_in[12];
  const float* bn0_m   = (const float*)d_in[13];
  const float* bn0_v   = (const float*)d_in[14];
  const float* lin0_w  = (const float*)d_in[15];
  const float* lin0_b  = (const float*)d_in[16];
  const float* p1_w    = (const float*)d_in[17];
  const float* p1_b    = (const float*)d_in[18];
  const float* bn1_g   = (const float*)d_in[19];
  const float* bn1_b   = (const float*)d_in[20];
  const float* bn1_m   = (const float*)d_in[21];
  const float* bn1_v   = (const float*)d_in[22];

  float* ws = (float*)d_ws;
  unsigned short* q16 = (unsigned short*)ws;       // 8,388,608 shorts (16MB)
  float* gf   = ws + 4194304;                      // 8,388,608 floats (32MB)
  unsigned short* t16 = (unsigned short*)(ws + 12582912);  // 8,388,608 shorts
  float* p0   = ws + 16777216;                     // 2,097,152
  float* lin0b= ws + 18874368;                     // 2,097,152
  float* p1   = ws + 20971520;                     // 524,288
  float* kvb  = ws + 21495808;                     // 1,048,576
  short* kT   = (short*)(ws + 22544384);           // 524,288 shorts
  short* vT   = kT + 524288;                       // 524,288 shorts

  // 1) q16 = bf16(pw(x, q_w) + q_b)
  pw_gemm_mfma<false, true><<<dim3(NHW / 128, 1, NB), 256, 0, stream>>>(
      q_w, q_b, x, q16, NHW, 128);
  // 2) p0 = bn0(dw5x5_s2(x) + p0_b)          -> 64x64
  dw5x5s2_tile<128, 128, 64, 16, 140><<<dim3(4, NC, NB), 256, 0, stream>>>(
      x, p0_w, p0_b, bn0_g, bn0_b, bn0_m, bn0_v, p0);
  // 3) lin0 = pw(p0, lin0_w) + lin0_b
  pw_gemm_mfma<false, false><<<dim3(4096 / 128, 1, NB), 256, 0, stream>>>(
      lin0_w, lin0_b, p0, lin0b, 4096, 128);
  // 4) p1 = bn1(dw5x5_s2(lin0) + p1_b)       -> 32x32
  dw5x5s2_tile<64, 64, 32, 32, 76><<<dim3(1, NC, NB), 256, 0, stream>>>(
      lin0b, p1_w, p1_b, bn1_g, bn1_b, bn1_m, bn1_v, p1);
  // 5) kv = pw(p1, kv_w) + kv_b   (256 out channels)
  pw_gemm_mfma<false, false><<<dim3(NKV / 128, 2, NB), 256, 0, stream>>>(
      kv_w, kv_b, p1, kvb, NKV, 256);
  // 6) kv -> bf16 kT [bh][kpos][32], vT [bh][d][kpos]
  kv_prep<<<dim3(4, 4, NB), 256, 0, stream>>>(kvb, kT, vT);
  // 7) split-K MFMA attention -> gf   (8 waves: 4 qgroups x 2 key halves)
  attn_mfma64<<<dim3(NHW / 256, 4, NB), 512, 0, stream>>>(q16, kT, vT, gf);
  // 8) lf dwconv + elementwise fuse -> t16 (bf16)
  lf_fuse_tile<<<dim3(16, NC, NB), 256, 0, stream>>>(q16, gf, local_w, local_b, t16);
  // 9) out = pw(t16, mixer_w) + mixer_b
  pw_gemm_mfma<true, false><<<dim3(NHW / 128, 1, NB), 256, 0, stream>>>(
      mixer_w, mixer_b, t16, (float*)d_out, NHW, 128);
}